// Round 1
// baseline (503.777 us; speedup 1.0000x reference)
//
#include <hip/hip_runtime.h>

typedef __attribute__((ext_vector_type(8))) __bf16 bf16x8;
typedef __attribute__((ext_vector_type(4))) float f32x4;
typedef __attribute__((ext_vector_type(8))) unsigned short u16x8;
typedef unsigned short u16;

__device__ __forceinline__ u16 f2bf(float f) {
  unsigned u = __builtin_bit_cast(unsigned, f);
  u = u + 0x7FFFu + ((u >> 16) & 1u);
  return (u16)(u >> 16);
}

__device__ __forceinline__ f32x4 mfma16(bf16x8 a, bf16x8 b, f32x4 c) {
  return __builtin_amdgcn_mfma_f32_16x16x32_bf16(a, b, c, 0, 0, 0);
}

__device__ __forceinline__ void gl_lds16(const void* g, void* l) {
  __builtin_amdgcn_global_load_lds(
      (const __attribute__((address_space(1))) unsigned int*)g,
      (__attribute__((address_space(3))) unsigned int*)l, 16, 0, 0);
}

// ---------------- transpose + f32->bf16 convert: out[n][k] = bf16(in[k][n]) ----------
__global__ void convT(const float* __restrict__ in, u16* __restrict__ outT, int K, int N) {
  const unsigned kq = (unsigned)K >> 2;
  const unsigned total = (unsigned)N * kq;
  for (unsigned i = blockIdx.x * blockDim.x + threadIdx.x; i < total;
       i += gridDim.x * blockDim.x) {
    const unsigned n = i / kq;
    const unsigned k4 = (i % kq) << 2;
    ushort4 o;
    o.x = f2bf(in[(size_t)(k4 + 0) * N + n]);
    o.y = f2bf(in[(size_t)(k4 + 1) * N + n]);
    o.z = f2bf(in[(size_t)(k4 + 2) * N + n]);
    o.w = f2bf(in[(size_t)(k4 + 3) * N + n]);
    *(ushort4*)(outT + (size_t)n * K + k4) = o;
  }
}

// ---------------- LayerNorm (C=1024 fixed), fp32 in -> bf16 out ----------------------
__global__ __launch_bounds__(256) void ln_bf16(const float* __restrict__ x,
                                               const float* __restrict__ wgt,
                                               u16* __restrict__ out) {
  const int row = blockIdx.x, t = threadIdx.x;
  const float4 v = ((const float4*)(x + (size_t)row * 1024))[t];
  float s = v.x + v.y + v.z + v.w;
  float q = v.x * v.x + v.y * v.y + v.z * v.z + v.w * v.w;
#pragma unroll
  for (int d = 32; d; d >>= 1) { s += __shfl_xor(s, d); q += __shfl_xor(q, d); }
  __shared__ float sb[8];
  const int wv = t >> 6;
  if ((t & 63) == 0) { sb[wv] = s; sb[4 + wv] = q; }
  __syncthreads();
  s = sb[0] + sb[1] + sb[2] + sb[3];
  q = sb[4] + sb[5] + sb[6] + sb[7];
  const float mu = s * (1.f / 1024.f);
  const float rstd = rsqrtf(q * (1.f / 1024.f) - mu * mu + 1e-5f);
  const float4 w4 = ((const float4*)wgt)[t];
  ushort4 o;
  o.x = f2bf((v.x - mu) * rstd * w4.x);
  o.y = f2bf((v.y - mu) * rstd * w4.y);
  o.z = f2bf((v.z - mu) * rstd * w4.z);
  o.w = f2bf((v.w - mu) * rstd * w4.w);
  *(ushort4*)(out + (size_t)row * 1024 + t * 4) = o;
}

// ---------------- 128x128 bf16 MFMA GEMM, A[M][K] x Bt[N][K]^T -> out[M][N] ----------
// EPI 0: out bf16 = acc ; EPI 1: out f32 = res + acc ; EPI 2: out bf16 = relu(acc)
template <int EPI>
__global__ __launch_bounds__(256) void gemm128(const u16* __restrict__ A,
                                               const u16* __restrict__ Bt,
                                               void* __restrict__ outp,
                                               const float* __restrict__ res,
                                               int M, int N, int K) {
  __shared__ u16 As[4096];  // [128][32]
  __shared__ u16 Bs[4096];  // [128 n][32 k]
  const int t = threadIdx.x, w = t >> 6, l = t & 63;
  const int lr = l & 15, g = l >> 4;
  const int row0 = blockIdx.y * 128, col0 = blockIdx.x * 128;
  const int wr = w >> 1, wc = w & 1;
  f32x4 acc[4][4] = {};

  const int sr = t >> 2;        // staging row 0..63
  const int sk = (t & 3) << 3;  // staging k-offset
  const u16* Ag = A + (size_t)(row0 + sr) * K + sk;
  const u16* Bg = Bt + (size_t)(col0 + sr) * K + sk;
  u16* AsW = As + w * 512;      // wave-uniform LDS base (lane writes +l*16B)
  u16* BsW = Bs + w * 512;
  const size_t rstride = (size_t)64 * K;

  for (int kt = 0; kt < K; kt += 32) {
    __syncthreads();
    gl_lds16(Ag + kt, AsW);
    gl_lds16(Ag + kt + rstride, AsW + 2048);
    gl_lds16(Bg + kt, BsW);
    gl_lds16(Bg + kt + rstride, BsW + 2048);
    __syncthreads();
    bf16x8 af[4], bf[4];
#pragma unroll
    for (int m = 0; m < 4; ++m)
      af[m] = *(const bf16x8*)(As + (wr * 64 + m * 16 + lr) * 32 + g * 8);
#pragma unroll
    for (int n = 0; n < 4; ++n)
      bf[n] = *(const bf16x8*)(Bs + (wc * 64 + n * 16 + lr) * 32 + g * 8);
#pragma unroll
    for (int m = 0; m < 4; ++m)
#pragma unroll
      for (int n = 0; n < 4; ++n) acc[m][n] = mfma16(af[m], bf[n], acc[m][n]);
  }

#pragma unroll
  for (int m = 0; m < 4; ++m)
#pragma unroll
    for (int n = 0; n < 4; ++n)
#pragma unroll
      for (int r = 0; r < 4; ++r) {
        const int row = row0 + wr * 64 + m * 16 + g * 4 + r;
        const int col = col0 + wc * 64 + n * 16 + lr;
        const size_t idx = (size_t)row * N + col;
        const float v = acc[m][n][r];
        if constexpr (EPI == 0) ((u16*)outp)[idx] = f2bf(v);
        else if constexpr (EPI == 1) ((float*)outp)[idx] = res[idx] + v;
        else ((u16*)outp)[idx] = f2bf(fmaxf(v, 0.f));
      }
}

// ---------------- causal flash attention, bf16 MFMA ---------------------------------
// qkv: [B*T][3072] bf16 (q|k|v). y: [B*T][1024] bf16. grid (T/64, B*H), 256 thr.
__global__ __launch_bounds__(256) void attn_fwd(const u16* __restrict__ qkvb,
                                                u16* __restrict__ y) {
  const int T = 2048, LD = 3072, Dh = 64;
  const int qt = blockIdx.x, bh = blockIdx.y;
  const int b = bh >> 4, h = bh & 15;
  const int t = threadIdx.x, w = t >> 6, l = t & 63;
  const int lr = l & 15, g = l >> 4;
  const int q0 = qt * 64;
  const int q0w = q0 + w * 16;
  const size_t base = (size_t)b * T * LD;

  const u16* Qp = qkvb + base + (size_t)(q0w + lr) * LD + h * Dh;
  const bf16x8 qf0 = *(const bf16x8*)(Qp + g * 8);
  const bf16x8 qf1 = *(const bf16x8*)(Qp + 32 + g * 8);

  __shared__ u16 Vt[64][48];      // V^T: [dh][kv], padded stride 48 (96B, 16B-aligned)
  __shared__ u16 Pb[4][16][48];   // per-wave P tile [q][kv]

  f32x4 o[4] = {};
  float m_run[4] = {-1e30f, -1e30f, -1e30f, -1e30f};
  float s_run[4] = {0.f, 0.f, 0.f, 0.f};

  const int kv_end = q0 + 64;
  for (int kv0 = 0; kv0 < kv_end; kv0 += 32) {
    __syncthreads();
    {  // stage V^T tile (32 kv x 64 dh)
      const int kv = t >> 3, d0 = (t & 7) << 3;
      const u16* Vp = qkvb + base + (size_t)(kv0 + kv) * LD + 2048 + h * Dh + d0;
      const u16x8 vv = *(const u16x8*)Vp;
#pragma unroll
      for (int j = 0; j < 8; ++j) Vt[d0 + j][kv] = vv[j];
    }
    __syncthreads();

    f32x4 s[2];
#pragma unroll
    for (int i = 0; i < 2; ++i) {
      const u16* Kp = qkvb + base + (size_t)(kv0 + i * 16 + lr) * LD + 1024 + h * Dh;
      const bf16x8 kf0 = *(const bf16x8*)(Kp + g * 8);
      const bf16x8 kf1 = *(const bf16x8*)(Kp + 32 + g * 8);
      f32x4 z = {0.f, 0.f, 0.f, 0.f};
      z = mfma16(qf0, kf0, z);
      z = mfma16(qf1, kf1, z);
      s[i] = z * 0.03125f;  // scale by C^-0.5 = 1/32 (full embed dim, per reference)
    }
    if (kv0 + 31 > q0w) {  // causal mask
#pragma unroll
      for (int i = 0; i < 2; ++i) {
        const int col = kv0 + i * 16 + lr;
#pragma unroll
        for (int r = 0; r < 4; ++r) {
          const int row = q0w + g * 4 + r;
          if (col > row) s[i][r] = -1e30f;
        }
      }
    }
#pragma unroll
    for (int r = 0; r < 4; ++r) {  // online softmax over the 16-lane col groups
      float mx = fmaxf(s[0][r], s[1][r]);
#pragma unroll
      for (int d = 8; d; d >>= 1) mx = fmaxf(mx, __shfl_xor(mx, d));
      const float mnew = fmaxf(m_run[r], mx);
      const float sc = __expf(m_run[r] - mnew);
      const float p0 = __expf(s[0][r] - mnew);
      const float p1 = __expf(s[1][r] - mnew);
      float ps = p0 + p1;
#pragma unroll
      for (int d = 8; d; d >>= 1) ps += __shfl_xor(ps, d);
      s_run[r] = s_run[r] * sc + ps;
      m_run[r] = mnew;
#pragma unroll
      for (int n = 0; n < 4; ++n) o[n][r] *= sc;
      Pb[w][g * 4 + r][lr] = f2bf(p0);
      Pb[w][g * 4 + r][16 + lr] = f2bf(p1);
    }
    // PV (wave-internal LDS write->read; compiler orders via lgkmcnt)
    const bf16x8 pa = *(const bf16x8*)(&Pb[w][lr][g * 8]);
#pragma unroll
    for (int n = 0; n < 4; ++n) {
      const bf16x8 vf = *(const bf16x8*)(&Vt[n * 16 + lr][g * 8]);
      o[n] = mfma16(pa, vf, o[n]);
    }
  }

#pragma unroll
  for (int n = 0; n < 4; ++n)
#pragma unroll
    for (int r = 0; r < 4; ++r) {
      const int row = q0w + g * 4 + r;
      const int col = h * Dh + n * 16 + lr;
      y[(size_t)(b * T + row) * 1024 + col] = f2bf(o[n][r] / s_run[r]);
    }
}

// ------------------------------------------------------------------------------------
extern "C" void kernel_launch(void* const* d_in, const int* in_sizes, int n_in,
                              void* d_out, int out_size, void* d_ws, size_t ws_size,
                              hipStream_t stream) {
  const float* x      = (const float*)d_in[0];
  const float* ln1w   = (const float*)d_in[1];
  const float* wattn  = (const float*)d_in[2];
  const float* wproj  = (const float*)d_in[3];
  const float* ln2w   = (const float*)d_in[4];
  const float* wfc    = (const float*)d_in[5];
  const float* wcproj = (const float*)d_in[6];
  float* out = (float*)d_out;
  char* ws = (char*)d_ws;
  const size_t MB = 1024 * 1024;
  u16* h1      = (u16*)(ws + 0);         //  8 MB  [4096][1024] bf16
  u16* qkvb    = (u16*)(ws + 8 * MB);    // 24 MB  [4096][3072] bf16
  u16* yb      = (u16*)(ws + 32 * MB);   //  8 MB  [4096][1024] bf16
  float* x1    = (float*)(ws + 40 * MB); // 16 MB  [4096][1024] f32
  u16* h2      = (u16*)(ws + 56 * MB);   //  8 MB
  u16* hf      = (u16*)(ws + 64 * MB);   // 32 MB  [4096][4096] bf16
  u16* wattnT  = (u16*)(ws + 96 * MB);   //  6 MB  [3072][1024]
  u16* wprojT  = (u16*)(ws + 102 * MB);  //  2 MB  [1024][1024]
  u16* wfcT    = (u16*)(ws + 104 * MB);  //  8 MB  [4096][1024]
  u16* wcprojT = (u16*)(ws + 112 * MB);  //  8 MB  [1024][4096]

  convT<<<2048, 256, 0, stream>>>(wattn, wattnT, 1024, 3072);
  convT<<<1024, 256, 0, stream>>>(wproj, wprojT, 1024, 1024);
  convT<<<2048, 256, 0, stream>>>(wfc, wfcT, 1024, 4096);
  convT<<<2048, 256, 0, stream>>>(wcproj, wcprojT, 4096, 1024);

  ln_bf16<<<4096, 256, 0, stream>>>(x, ln1w, h1);
  gemm128<0><<<dim3(24, 32), 256, 0, stream>>>(h1, wattnT, qkvb, nullptr, 4096, 3072, 1024);
  attn_fwd<<<dim3(32, 32), 256, 0, stream>>>(qkvb, yb);
  gemm128<1><<<dim3(8, 32), 256, 0, stream>>>(yb, wprojT, x1, x, 4096, 1024, 1024);
  ln_bf16<<<4096, 256, 0, stream>>>(x1, ln2w, h2);
  gemm128<2><<<dim3(32, 32), 256, 0, stream>>>(h2, wfcT, hf, nullptr, 4096, 4096, 1024);
  gemm128<1><<<dim3(8, 32), 256, 0, stream>>>(hf, wcprojT, out, x1, 4096, 1024, 4096);
}

// Round 4
// 355.055 us; speedup vs baseline: 1.4189x; 1.4189x over previous
//
#include <hip/hip_runtime.h>

typedef __attribute__((ext_vector_type(8))) __bf16 bf16x8;
typedef __attribute__((ext_vector_type(4))) float f32x4;
typedef __attribute__((ext_vector_type(8))) unsigned short u16x8;
typedef unsigned short u16;

__device__ __forceinline__ u16 f2bf(float f) {
  unsigned u = __builtin_bit_cast(unsigned, f);
  u = u + 0x7FFFu + ((u >> 16) & 1u);
  return (u16)(u >> 16);
}

__device__ __forceinline__ f32x4 mfma16(bf16x8 a, bf16x8 b, f32x4 c) {
  return __builtin_amdgcn_mfma_f32_16x16x32_bf16(a, b, c, 0, 0, 0);
}

__device__ __forceinline__ void gl_lds16(const void* g, void* l) {
  __builtin_amdgcn_global_load_lds(
      (const __attribute__((address_space(1))) unsigned int*)g,
      (__attribute__((address_space(3))) unsigned int*)l, 16, 0, 0);
}

// ---------------- transpose + f32->bf16 convert: out[n][k] = bf16(in[k][n]) ----------
__global__ void convT(const float* __restrict__ in, u16* __restrict__ outT, int K, int N) {
  const unsigned kq = (unsigned)K >> 2;
  const unsigned total = (unsigned)N * kq;
  for (unsigned i = blockIdx.x * blockDim.x + threadIdx.x; i < total;
       i += gridDim.x * blockDim.x) {
    const unsigned n = i / kq;
    const unsigned k4 = (i % kq) << 2;
    ushort4 o;
    o.x = f2bf(in[(size_t)(k4 + 0) * N + n]);
    o.y = f2bf(in[(size_t)(k4 + 1) * N + n]);
    o.z = f2bf(in[(size_t)(k4 + 2) * N + n]);
    o.w = f2bf(in[(size_t)(k4 + 3) * N + n]);
    *(ushort4*)(outT + (size_t)n * K + k4) = o;
  }
}

// ---------------- LayerNorm (C=1024 fixed), fp32 in -> bf16 out ----------------------
__global__ __launch_bounds__(256) void ln_bf16(const float* __restrict__ x,
                                               const float* __restrict__ wgt,
                                               u16* __restrict__ out) {
  const int row = blockIdx.x, t = threadIdx.x;
  const float4 v = ((const float4*)(x + (size_t)row * 1024))[t];
  float s = v.x + v.y + v.z + v.w;
  float q = v.x * v.x + v.y * v.y + v.z * v.z + v.w * v.w;
#pragma unroll
  for (int d = 32; d; d >>= 1) { s += __shfl_xor(s, d); q += __shfl_xor(q, d); }
  __shared__ float sb[8];
  const int wv = t >> 6;
  if ((t & 63) == 0) { sb[wv] = s; sb[4 + wv] = q; }
  __syncthreads();
  s = sb[0] + sb[1] + sb[2] + sb[3];
  q = sb[4] + sb[5] + sb[6] + sb[7];
  const float mu = s * (1.f / 1024.f);
  const float rstd = rsqrtf(q * (1.f / 1024.f) - mu * mu + 1e-5f);
  const float4 w4 = ((const float4*)wgt)[t];
  ushort4 o;
  o.x = f2bf((v.x - mu) * rstd * w4.x);
  o.y = f2bf((v.y - mu) * rstd * w4.y);
  o.z = f2bf((v.z - mu) * rstd * w4.z);
  o.w = f2bf((v.w - mu) * rstd * w4.w);
  *(ushort4*)(out + (size_t)row * 1024 + t * 4) = o;
}

// ---------------- 128x128 bf16 MFMA GEMM, A[M][K] x Bt[N][K]^T -> out[M][N] ----------
// 2-phase double-buffered staging (issue next before compute, drain at barrier).
// EPI 0: out bf16 = acc ; EPI 1: out f32 = res + acc ; EPI 2: out bf16 = relu(acc)
template <int EPI>
__global__ __launch_bounds__(256) void gemm128(const u16* __restrict__ A,
                                               const u16* __restrict__ Bt,
                                               void* __restrict__ outp,
                                               const float* __restrict__ res,
                                               int M, int N, int K) {
  __shared__ u16 As[2][4096];  // [128][32]
  __shared__ u16 Bs[2][4096];  // [128 n][32 k]
  const int t = threadIdx.x, w = t >> 6, l = t & 63;
  const int lr = l & 15, g = l >> 4;
  const int row0 = blockIdx.y * 128, col0 = blockIdx.x * 128;
  const int wr = w >> 1, wc = w & 1;
  f32x4 acc[4][4] = {};

  const int sr = t >> 2;        // staging row 0..63
  const int sk = (t & 3) << 3;  // staging k-offset
  const u16* Ag = A + (size_t)(row0 + sr) * K + sk;
  const u16* Bg = Bt + (size_t)(col0 + sr) * K + sk;
  const size_t rstride = (size_t)64 * K;

  auto stage = [&](int kt, int bb) {
    u16* AsW = As[bb] + w * 512;
    u16* BsW = Bs[bb] + w * 512;
    gl_lds16(Ag + kt, AsW);
    gl_lds16(Ag + kt + rstride, AsW + 2048);
    gl_lds16(Bg + kt, BsW);
    gl_lds16(Bg + kt + rstride, BsW + 2048);
  };

  stage(0, 0);
  __syncthreads();
  int cur = 0;
  for (int kt = 0; kt < K; kt += 32) {
    if (kt + 32 < K) stage(kt + 32, cur ^ 1);
    bf16x8 af[4], bfr[4];
#pragma unroll
    for (int m = 0; m < 4; ++m)
      af[m] = *(const bf16x8*)(As[cur] + (wr * 64 + m * 16 + lr) * 32 + g * 8);
#pragma unroll
    for (int n = 0; n < 4; ++n)
      bfr[n] = *(const bf16x8*)(Bs[cur] + (wc * 64 + n * 16 + lr) * 32 + g * 8);
#pragma unroll
    for (int m = 0; m < 4; ++m)
#pragma unroll
      for (int n = 0; n < 4; ++n) acc[m][n] = mfma16(af[m], bfr[n], acc[m][n]);
    __syncthreads();
    cur ^= 1;
  }

#pragma unroll
  for (int m = 0; m < 4; ++m)
#pragma unroll
    for (int n = 0; n < 4; ++n)
#pragma unroll
      for (int r = 0; r < 4; ++r) {
        const int row = row0 + wr * 64 + m * 16 + g * 4 + r;
        const int col = col0 + wc * 64 + n * 16 + lr;
        const size_t idx = (size_t)row * N + col;
        const float v = acc[m][n][r];
        if constexpr (EPI == 0) ((u16*)outp)[idx] = f2bf(v);
        else if constexpr (EPI == 1) ((float*)outp)[idx] = res[idx] + v;
        else ((u16*)outp)[idx] = f2bf(fmaxf(v, 0.f));
      }
}

// ---------------- causal flash attention, bf16 MFMA ---------------------------------
// KVBLK=64, double-buffered.
// K tile: LDS row-major [64 kv][64 k], XOR swizzle byte^=( (row&7)<<4 ) applied on the
//         pre-swizzled global source of global_load_lds (linear dest) and on reads.
// V tile: LDS transposed [64 dh][stride 80 kv], staged via registers (coalesced u16x8
//         global loads + scalar ds_write_b16) -- the R0-verified pattern, no tr_read.
// grid (16, B*H); block handles q-tiles qt and 31-qt (uniform 33 kv-tiles).
__global__ __launch_bounds__(256) void attn_fwd(const u16* __restrict__ qkvb,
                                                u16* __restrict__ y) {
  __shared__ u16 Ks[2][4096];      // 2 x 8KB
  __shared__ u16 Vt[2][64 * 80];   // 2 x 10KB, [dh][kv] stride 80
  __shared__ u16 Pb[4][16 * 72];   // per-wave P: [q 0..15][kv 0..63], stride 72
  const int t = threadIdx.x, w = t >> 6, l = t & 63;
  const int lr = l & 15, g = l >> 4;
  const int bh = blockIdx.y, b = bh >> 4, h = bh & 15;
  const size_t base = (size_t)b * 2048 * 3072;
  const u16* Kg = qkvb + base + 1024 + h * 64;
  const u16* Vg = qkvb + base + 2048 + h * 64;
  u16* Pw = &Pb[w][0];
  const int vkv = t & 63;          // V staging: kv row
  const int vd0 = (t >> 6) * 16;   // V staging: dh chunk base

  auto stageK = [&](int kv0, int bb) {
#pragma unroll
    for (int r = 0; r < 2; ++r) {
      const int dl = (r * 256 + t) * 16;                  // dest byte in 8KB tile
      const int row = dl >> 7;
      const int srcb = (dl & 127) ^ ((row & 7) << 4);     // inverse-swizzled source
      gl_lds16(Kg + (size_t)(kv0 + row) * 3072 + (srcb >> 1),
               (char*)Ks[bb] + r * 4096 + w * 1024);
    }
  };

  for (int pass = 0; pass < 2; ++pass) {
    const int qt = (pass == 0) ? blockIdx.x : 31 - blockIdx.x;
    const int q0 = qt * 64, q0w = q0 + w * 16, nt = qt + 1;
    const u16* Qp = qkvb + base + (size_t)(q0w + lr) * 3072 + h * 64;
    const bf16x8 qf0 = *(const bf16x8*)(Qp + g * 8);
    const bf16x8 qf1 = *(const bf16x8*)(Qp + 32 + g * 8);
    f32x4 o[4] = {};
    float m_run[4] = {-1e30f, -1e30f, -1e30f, -1e30f};
    float s_lane[4] = {0.f, 0.f, 0.f, 0.f};

    // prologue: stage tile 0
    stageK(0, 0);
    u16x8 v0 = *(const u16x8*)(Vg + (size_t)vkv * 3072 + vd0);
    u16x8 v1 = *(const u16x8*)(Vg + (size_t)vkv * 3072 + vd0 + 8);
#pragma unroll
    for (int j = 0; j < 8; ++j) {
      Vt[0][(vd0 + j) * 80 + vkv] = v0[j];
      Vt[0][(vd0 + 8 + j) * 80 + vkv] = v1[j];
    }
    __syncthreads();

    int ct = 0;
    for (int tt = 0; tt < nt; ++tt) {
      const int kv0 = tt * 64;
      const bool more = (tt + 1 < nt);
      if (more) {  // issue next-tile staging early (T14): K direct-to-LDS, V to regs
        stageK(kv0 + 64, ct ^ 1);
        v0 = *(const u16x8*)(Vg + (size_t)(kv0 + 64 + vkv) * 3072 + vd0);
        v1 = *(const u16x8*)(Vg + (size_t)(kv0 + 64 + vkv) * 3072 + vd0 + 8);
      }

      const u16* Kbuf = Ks[ct];
      // ---- QK^T (K=64 over two halves), swizzled K reads ----
      f32x4 s4[4];
#pragma unroll
      for (int i = 0; i < 4; ++i) {
        const int row = i * 16 + lr;
        const int sw = (row & 7) << 4;
        const bf16x8 k0 = *(const bf16x8*)(Kbuf + row * 64 + (((g * 16) ^ sw) >> 1));
        const bf16x8 k1 = *(const bf16x8*)(Kbuf + row * 64 + (((64 + g * 16) ^ sw) >> 1));
        f32x4 z = {0.f, 0.f, 0.f, 0.f};
        z = mfma16(qf0, k0, z);
        z = mfma16(qf1, k1, z);
        s4[i] = z * 0.03125f;  // * C^-0.5 = 1/32 (full embed dim, per reference)
      }
      if (kv0 + 64 > q0w) {  // causal mask (diagonal tile only)
#pragma unroll
        for (int i = 0; i < 4; ++i) {
          const int col = kv0 + i * 16 + lr;
#pragma unroll
          for (int r = 0; r < 4; ++r)
            if (col > q0w + g * 4 + r) s4[i][r] = -1e30f;
        }
      }
      // ---- online softmax (row = g*4+r spread over 16 lr lanes x 4 regs) ----
#pragma unroll
      for (int r = 0; r < 4; ++r) {
        float mx = fmaxf(fmaxf(s4[0][r], s4[1][r]), fmaxf(s4[2][r], s4[3][r]));
        mx = fmaxf(mx, __shfl_xor(mx, 1));
        mx = fmaxf(mx, __shfl_xor(mx, 2));
        mx = fmaxf(mx, __shfl_xor(mx, 4));
        mx = fmaxf(mx, __shfl_xor(mx, 8));
        const float mnew = fmaxf(m_run[r], mx);
        const float sc = __expf(m_run[r] - mnew);
        m_run[r] = mnew;
        const float p0 = __expf(s4[0][r] - mnew), p1 = __expf(s4[1][r] - mnew);
        const float p2 = __expf(s4[2][r] - mnew), p3 = __expf(s4[3][r] - mnew);
        s_lane[r] = s_lane[r] * sc + (p0 + p1) + (p2 + p3);  // deferred denominator
        o[0][r] *= sc; o[1][r] *= sc; o[2][r] *= sc; o[3][r] *= sc;
        const int pr = (g * 4 + r) * 72 + lr;
        Pw[pr] = f2bf(p0); Pw[pr + 16] = f2bf(p1);
        Pw[pr + 32] = f2bf(p2); Pw[pr + 48] = f2bf(p3);
      }
      // ---- PV: P a-frag (same-wave LDS bounce), V b-frag contiguous from Vt ----
#pragma unroll
      for (int s = 0; s < 2; ++s) {
        const bf16x8 pa = *(const bf16x8*)(Pw + lr * 72 + s * 32 + g * 8);
#pragma unroll
        for (int n = 0; n < 4; ++n) {
          const bf16x8 vf =
              *(const bf16x8*)(&Vt[ct][(n * 16 + lr) * 80 + s * 32 + g * 8]);
          o[n] = mfma16(pa, vf, o[n]);
        }
      }
      if (more) {  // write next V tile (loads have had the whole tile to land)
#pragma unroll
        for (int j = 0; j < 8; ++j) {
          Vt[ct ^ 1][(vd0 + j) * 80 + vkv] = v0[j];
          Vt[ct ^ 1][(vd0 + 8 + j) * 80 + vkv] = v1[j];
        }
      }
      __syncthreads();
      ct ^= 1;
    }

    // ---- epilogue: reduce deferred denominators, write y ----
    float inv[4];
#pragma unroll
    for (int r = 0; r < 4; ++r) {
      float den = s_lane[r];
      den += __shfl_xor(den, 1);
      den += __shfl_xor(den, 2);
      den += __shfl_xor(den, 4);
      den += __shfl_xor(den, 8);
      inv[r] = 1.f / den;
    }
#pragma unroll
    for (int n = 0; n < 4; ++n)
#pragma unroll
      for (int r = 0; r < 4; ++r) {
        const int row = q0w + g * 4 + r;
        const int col = h * 64 + n * 16 + lr;
        y[(size_t)(b * 2048 + row) * 1024 + col] = f2bf(o[n][r] * inv[r]);
      }
  }
}

// ------------------------------------------------------------------------------------
extern "C" void kernel_launch(void* const* d_in, const int* in_sizes, int n_in,
                              void* d_out, int out_size, void* d_ws, size_t ws_size,
                              hipStream_t stream) {
  const float* x      = (const float*)d_in[0];
  const float* ln1w   = (const float*)d_in[1];
  const float* wattn  = (const float*)d_in[2];
  const float* wproj  = (const float*)d_in[3];
  const float* ln2w   = (const float*)d_in[4];
  const float* wfc    = (const float*)d_in[5];
  const float* wcproj = (const float*)d_in[6];
  float* out = (float*)d_out;
  char* ws = (char*)d_ws;
  const size_t MB = 1024 * 1024;
  u16* h1      = (u16*)(ws + 0);         //  8 MB  [4096][1024] bf16
  u16* qkvb    = (u16*)(ws + 8 * MB);    // 24 MB  [4096][3072] bf16
  u16* yb      = (u16*)(ws + 32 * MB);   //  8 MB  [4096][1024] bf16
  float* x1    = (float*)(ws + 40 * MB); // 16 MB  [4096][1024] f32
  u16* h2      = (u16*)(ws + 56 * MB);   //  8 MB
  u16* hf      = (u16*)(ws + 64 * MB);   // 32 MB  [4096][4096] bf16
  u16* wattnT  = (u16*)(ws + 96 * MB);   //  6 MB  [3072][1024]
  u16* wprojT  = (u16*)(ws + 102 * MB);  //  2 MB  [1024][1024]
  u16* wfcT    = (u16*)(ws + 104 * MB);  //  8 MB  [4096][1024]
  u16* wcprojT = (u16*)(ws + 112 * MB);  //  8 MB  [1024][4096]

  convT<<<2048, 256, 0, stream>>>(wattn, wattnT, 1024, 3072);
  convT<<<1024, 256, 0, stream>>>(wproj, wprojT, 1024, 1024);
  convT<<<2048, 256, 0, stream>>>(wfc, wfcT, 1024, 4096);
  convT<<<2048, 256, 0, stream>>>(wcproj, wcprojT, 4096, 1024);

  ln_bf16<<<4096, 256, 0, stream>>>(x, ln1w, h1);
  gemm128<0><<<dim3(24, 32), 256, 0, stream>>>(h1, wattnT, qkvb, nullptr, 4096, 3072, 1024);
  attn_fwd<<<dim3(16, 32), 256, 0, stream>>>(qkvb, yb);
  gemm128<1><<<dim3(8, 32), 256, 0, stream>>>(yb, wprojT, x1, x, 4096, 1024, 1024);
  ln_bf16<<<4096, 256, 0, stream>>>(x1, ln2w, h2);
  gemm128<2><<<dim3(32, 32), 256, 0, stream>>>(h2, wfcT, hf, nullptr, 4096, 4096, 1024);
  gemm128<1><<<dim3(8, 32), 256, 0, stream>>>(hf, wcprojT, out, x1, 4096, 1024, 4096);
}

// Round 5
// 322.978 us; speedup vs baseline: 1.5598x; 1.0993x over previous
//
#include <hip/hip_runtime.h>

typedef __attribute__((ext_vector_type(8))) __bf16 bf16x8;
typedef __attribute__((ext_vector_type(4))) float f32x4;
typedef __attribute__((ext_vector_type(8))) unsigned short u16x8;
typedef unsigned short u16;

__device__ __forceinline__ u16 f2bf(float f) {
  unsigned u = __builtin_bit_cast(unsigned, f);
  u = u + 0x7FFFu + ((u >> 16) & 1u);
  return (u16)(u >> 16);
}

__device__ __forceinline__ f32x4 mfma16(bf16x8 a, bf16x8 b, f32x4 c) {
  return __builtin_amdgcn_mfma_f32_16x16x32_bf16(a, b, c, 0, 0, 0);
}

__device__ __forceinline__ void gl_lds16(const void* g, void* l) {
  __builtin_amdgcn_global_load_lds(
      (const __attribute__((address_space(1))) unsigned int*)g,
      (__attribute__((address_space(3))) unsigned int*)l, 16, 0, 0);
}

// ---------------- coalesced tiled transpose+convert: out[n][k] = bf16(in[k][n]) ------
// grid (K/64, N/64), 256 threads, LDS tile [64][65] f32.
__global__ __launch_bounds__(256) void convT(const float* __restrict__ in,
                                             u16* __restrict__ outT, int K, int N) {
  __shared__ float tile[64][65];
  const int t = threadIdx.x;
  const int tk = blockIdx.x * 64, tn = blockIdx.y * 64;
  const int lk = t >> 4, ln = (t & 15) * 4;
#pragma unroll
  for (int r = 0; r < 4; ++r) {
    const int k = lk + r * 16;
    const float4 v = *(const float4*)(in + (size_t)(tk + k) * N + tn + ln);
    tile[k][ln + 0] = v.x; tile[k][ln + 1] = v.y;
    tile[k][ln + 2] = v.z; tile[k][ln + 3] = v.w;
  }
  __syncthreads();
  const int sn = t >> 2, sk = (t & 3) * 4;
#pragma unroll
  for (int j = 0; j < 4; ++j) {
    const int k = sk + j * 16;
    ushort4 o;
    o.x = f2bf(tile[k + 0][sn]); o.y = f2bf(tile[k + 1][sn]);
    o.z = f2bf(tile[k + 2][sn]); o.w = f2bf(tile[k + 3][sn]);
    *(ushort4*)(outT + (size_t)(tn + sn) * K + tk + k) = o;
  }
}

// ---------------- vectorized f32 copy (residual pre-fill for split-K atomics) --------
__global__ __launch_bounds__(256) void fill_f32(const float* __restrict__ src,
                                                float* __restrict__ dst, int n4) {
  const int i = blockIdx.x * blockDim.x + threadIdx.x;
  if (i < n4) ((float4*)dst)[i] = ((const float4*)src)[i];
}

// ---------------- LayerNorm (C=1024 fixed), fp32 in -> bf16 out ----------------------
__global__ __launch_bounds__(256) void ln_bf16(const float* __restrict__ x,
                                               const float* __restrict__ wgt,
                                               u16* __restrict__ out) {
  const int row = blockIdx.x, t = threadIdx.x;
  const float4 v = ((const float4*)(x + (size_t)row * 1024))[t];
  float s = v.x + v.y + v.z + v.w;
  float q = v.x * v.x + v.y * v.y + v.z * v.z + v.w * v.w;
#pragma unroll
  for (int d = 32; d; d >>= 1) { s += __shfl_xor(s, d); q += __shfl_xor(q, d); }
  __shared__ float sb[8];
  const int wv = t >> 6;
  if ((t & 63) == 0) { sb[wv] = s; sb[4 + wv] = q; }
  __syncthreads();
  s = sb[0] + sb[1] + sb[2] + sb[3];
  q = sb[4] + sb[5] + sb[6] + sb[7];
  const float mu = s * (1.f / 1024.f);
  const float rstd = rsqrtf(q * (1.f / 1024.f) - mu * mu + 1e-5f);
  const float4 w4 = ((const float4*)wgt)[t];
  ushort4 o;
  o.x = f2bf((v.x - mu) * rstd * w4.x);
  o.y = f2bf((v.y - mu) * rstd * w4.y);
  o.z = f2bf((v.z - mu) * rstd * w4.z);
  o.w = f2bf((v.w - mu) * rstd * w4.w);
  *(ushort4*)(out + (size_t)row * 1024 + t * 4) = o;
}

// ---------------- 128x128 bf16 MFMA GEMM, A[M][K] x Bt[N][K]^T -> out[M][N] ----------
// 2-phase double-buffered staging; split-K via gridDim.z (EPI 3); XCD-swizzled ids.
// EPI 0: out bf16 = acc ; EPI 2: out bf16 = relu(acc) ; EPI 3: atomicAdd f32 += acc
template <int EPI>
__global__ __launch_bounds__(256) void gemm128(const u16* __restrict__ A,
                                               const u16* __restrict__ Bt,
                                               void* __restrict__ outp,
                                               int M, int N, int K) {
  __shared__ u16 As[2][4096];  // [128][32]
  __shared__ u16 Bs[2][4096];  // [128 n][32 k]
  // XCD-aware bijective swizzle on the full flat id (all grids are %8 == 0)
  const unsigned gx = gridDim.x, gy = gridDim.y, gxy = gx * gy;
  const unsigned nwg = gxy * gridDim.z;
  unsigned f = (blockIdx.z * gy + blockIdx.y) * gx + blockIdx.x;
  if ((nwg & 7u) == 0u) { const unsigned qq = nwg >> 3; f = (f & 7u) * qq + (f >> 3); }
  const int bx = f % gx, by = (f / gx) % gy, bz = f / gxy;

  const int t = threadIdx.x, w = t >> 6, l = t & 63;
  const int lr = l & 15, g = l >> 4;
  const int row0 = by * 128, col0 = bx * 128;
  const int segK = K / gridDim.z;
  const int k0 = bz * segK, kend = k0 + segK;
  const int wr = w >> 1, wc = w & 1;
  f32x4 acc[4][4] = {};

  const int sr = t >> 2;        // staging row 0..63
  const int sk = (t & 3) << 3;  // staging k-offset
  const u16* Ag = A + (size_t)(row0 + sr) * K + sk;
  const u16* Bg = Bt + (size_t)(col0 + sr) * K + sk;
  const size_t rstride = (size_t)64 * K;

  auto stage = [&](int kt, int bb) {
    u16* AsW = As[bb] + w * 512;
    u16* BsW = Bs[bb] + w * 512;
    gl_lds16(Ag + kt, AsW);
    gl_lds16(Ag + kt + rstride, AsW + 2048);
    gl_lds16(Bg + kt, BsW);
    gl_lds16(Bg + kt + rstride, BsW + 2048);
  };

  stage(k0, 0);
  __syncthreads();
  int cur = 0;
  for (int kt = k0; kt < kend; kt += 32) {
    if (kt + 32 < kend) stage(kt + 32, cur ^ 1);
    bf16x8 af[4], bfr[4];
#pragma unroll
    for (int m = 0; m < 4; ++m)
      af[m] = *(const bf16x8*)(As[cur] + (wr * 64 + m * 16 + lr) * 32 + g * 8);
#pragma unroll
    for (int n = 0; n < 4; ++n)
      bfr[n] = *(const bf16x8*)(Bs[cur] + (wc * 64 + n * 16 + lr) * 32 + g * 8);
#pragma unroll
    for (int m = 0; m < 4; ++m)
#pragma unroll
      for (int n = 0; n < 4; ++n) acc[m][n] = mfma16(af[m], bfr[n], acc[m][n]);
    __syncthreads();
    cur ^= 1;
  }

#pragma unroll
  for (int m = 0; m < 4; ++m)
#pragma unroll
    for (int n = 0; n < 4; ++n)
#pragma unroll
      for (int r = 0; r < 4; ++r) {
        const int row = row0 + wr * 64 + m * 16 + g * 4 + r;
        const int col = col0 + wc * 64 + n * 16 + lr;
        const size_t idx = (size_t)row * N + col;
        const float v = acc[m][n][r];
        if constexpr (EPI == 0) ((u16*)outp)[idx] = f2bf(v);
        else if constexpr (EPI == 2) ((u16*)outp)[idx] = f2bf(fmaxf(v, 0.f));
        else atomicAdd((float*)outp + idx, v);
      }
}

// ---------------- causal flash attention, bf16 MFMA (R4-verified) --------------------
__global__ __launch_bounds__(256) void attn_fwd(const u16* __restrict__ qkvb,
                                                u16* __restrict__ y) {
  __shared__ u16 Ks[2][4096];      // 2 x 8KB
  __shared__ u16 Vt[2][64 * 80];   // 2 x 10KB, [dh][kv] stride 80
  __shared__ u16 Pb[4][16 * 72];   // per-wave P: [q 0..15][kv 0..63], stride 72
  const int t = threadIdx.x, w = t >> 6, l = t & 63;
  const int lr = l & 15, g = l >> 4;
  const int bh = blockIdx.y, b = bh >> 4, h = bh & 15;
  const size_t base = (size_t)b * 2048 * 3072;
  const u16* Kg = qkvb + base + 1024 + h * 64;
  const u16* Vg = qkvb + base + 2048 + h * 64;
  u16* Pw = &Pb[w][0];
  const int vkv = t & 63;          // V staging: kv row
  const int vd0 = (t >> 6) * 16;   // V staging: dh chunk base

  auto stageK = [&](int kv0, int bb) {
#pragma unroll
    for (int r = 0; r < 2; ++r) {
      const int dl = (r * 256 + t) * 16;                  // dest byte in 8KB tile
      const int row = dl >> 7;
      const int srcb = (dl & 127) ^ ((row & 7) << 4);     // inverse-swizzled source
      gl_lds16(Kg + (size_t)(kv0 + row) * 3072 + (srcb >> 1),
               (char*)Ks[bb] + r * 4096 + w * 1024);
    }
  };

  for (int pass = 0; pass < 2; ++pass) {
    const int qt = (pass == 0) ? blockIdx.x : 31 - blockIdx.x;
    const int q0 = qt * 64, q0w = q0 + w * 16, nt = qt + 1;
    const u16* Qp = qkvb + base + (size_t)(q0w + lr) * 3072 + h * 64;
    const bf16x8 qf0 = *(const bf16x8*)(Qp + g * 8);
    const bf16x8 qf1 = *(const bf16x8*)(Qp + 32 + g * 8);
    f32x4 o[4] = {};
    float m_run[4] = {-1e30f, -1e30f, -1e30f, -1e30f};
    float s_lane[4] = {0.f, 0.f, 0.f, 0.f};

    stageK(0, 0);
    u16x8 v0 = *(const u16x8*)(Vg + (size_t)vkv * 3072 + vd0);
    u16x8 v1 = *(const u16x8*)(Vg + (size_t)vkv * 3072 + vd0 + 8);
#pragma unroll
    for (int j = 0; j < 8; ++j) {
      Vt[0][(vd0 + j) * 80 + vkv] = v0[j];
      Vt[0][(vd0 + 8 + j) * 80 + vkv] = v1[j];
    }
    __syncthreads();

    int ct = 0;
    for (int tt = 0; tt < nt; ++tt) {
      const int kv0 = tt * 64;
      const bool more = (tt + 1 < nt);
      if (more) {  // issue next-tile staging early (T14): K direct-to-LDS, V to regs
        stageK(kv0 + 64, ct ^ 1);
        v0 = *(const u16x8*)(Vg + (size_t)(kv0 + 64 + vkv) * 3072 + vd0);
        v1 = *(const u16x8*)(Vg + (size_t)(kv0 + 64 + vkv) * 3072 + vd0 + 8);
      }

      const u16* Kbuf = Ks[ct];
      // ---- QK^T (K=64 over two halves), swizzled K reads ----
      f32x4 s4[4];
#pragma unroll
      for (int i = 0; i < 4; ++i) {
        const int row = i * 16 + lr;
        const int sw = (row & 7) << 4;
        const bf16x8 k0 = *(const bf16x8*)(Kbuf + row * 64 + (((g * 16) ^ sw) >> 1));
        const bf16x8 k1 = *(const bf16x8*)(Kbuf + row * 64 + (((64 + g * 16) ^ sw) >> 1));
        f32x4 z = {0.f, 0.f, 0.f, 0.f};
        z = mfma16(qf0, k0, z);
        z = mfma16(qf1, k1, z);
        s4[i] = z * 0.03125f;  // * C^-0.5 = 1/32 (full embed dim, per reference)
      }
      if (kv0 + 64 > q0w) {  // causal mask (diagonal tile only)
#pragma unroll
        for (int i = 0; i < 4; ++i) {
          const int col = kv0 + i * 16 + lr;
#pragma unroll
          for (int r = 0; r < 4; ++r)
            if (col > q0w + g * 4 + r) s4[i][r] = -1e30f;
        }
      }
      // ---- online softmax ----
#pragma unroll
      for (int r = 0; r < 4; ++r) {
        float mx = fmaxf(fmaxf(s4[0][r], s4[1][r]), fmaxf(s4[2][r], s4[3][r]));
        mx = fmaxf(mx, __shfl_xor(mx, 1));
        mx = fmaxf(mx, __shfl_xor(mx, 2));
        mx = fmaxf(mx, __shfl_xor(mx, 4));
        mx = fmaxf(mx, __shfl_xor(mx, 8));
        const float mnew = fmaxf(m_run[r], mx);
        const float sc = __expf(m_run[r] - mnew);
        m_run[r] = mnew;
        const float p0 = __expf(s4[0][r] - mnew), p1 = __expf(s4[1][r] - mnew);
        const float p2 = __expf(s4[2][r] - mnew), p3 = __expf(s4[3][r] - mnew);
        s_lane[r] = s_lane[r] * sc + (p0 + p1) + (p2 + p3);  // deferred denominator
        o[0][r] *= sc; o[1][r] *= sc; o[2][r] *= sc; o[3][r] *= sc;
        const int pr = (g * 4 + r) * 72 + lr;
        Pw[pr] = f2bf(p0); Pw[pr + 16] = f2bf(p1);
        Pw[pr + 32] = f2bf(p2); Pw[pr + 48] = f2bf(p3);
      }
      // ---- PV ----
#pragma unroll
      for (int s = 0; s < 2; ++s) {
        const bf16x8 pa = *(const bf16x8*)(Pw + lr * 72 + s * 32 + g * 8);
#pragma unroll
        for (int n = 0; n < 4; ++n) {
          const bf16x8 vf =
              *(const bf16x8*)(&Vt[ct][(n * 16 + lr) * 80 + s * 32 + g * 8]);
          o[n] = mfma16(pa, vf, o[n]);
        }
      }
      if (more) {  // write next V tile
#pragma unroll
        for (int j = 0; j < 8; ++j) {
          Vt[ct ^ 1][(vd0 + j) * 80 + vkv] = v0[j];
          Vt[ct ^ 1][(vd0 + 8 + j) * 80 + vkv] = v1[j];
        }
      }
      __syncthreads();
      ct ^= 1;
    }

    // ---- epilogue ----
    float inv[4];
#pragma unroll
    for (int r = 0; r < 4; ++r) {
      float den = s_lane[r];
      den += __shfl_xor(den, 1);
      den += __shfl_xor(den, 2);
      den += __shfl_xor(den, 4);
      den += __shfl_xor(den, 8);
      inv[r] = 1.f / den;
    }
#pragma unroll
    for (int n = 0; n < 4; ++n)
#pragma unroll
      for (int r = 0; r < 4; ++r) {
        const int row = q0w + g * 4 + r;
        const int col = h * 64 + n * 16 + lr;
        y[(size_t)(b * 2048 + row) * 1024 + col] = f2bf(o[n][r] * inv[r]);
      }
  }
}

// ------------------------------------------------------------------------------------
extern "C" void kernel_launch(void* const* d_in, const int* in_sizes, int n_in,
                              void* d_out, int out_size, void* d_ws, size_t ws_size,
                              hipStream_t stream) {
  const float* x      = (const float*)d_in[0];
  const float* ln1w   = (const float*)d_in[1];
  const float* wattn  = (const float*)d_in[2];
  const float* wproj  = (const float*)d_in[3];
  const float* ln2w   = (const float*)d_in[4];
  const float* wfc    = (const float*)d_in[5];
  const float* wcproj = (const float*)d_in[6];
  float* out = (float*)d_out;
  char* ws = (char*)d_ws;
  const size_t MB = 1024 * 1024;
  u16* h1      = (u16*)(ws + 0);         //  8 MB  [4096][1024] bf16
  u16* qkvb    = (u16*)(ws + 8 * MB);    // 24 MB  [4096][3072] bf16
  u16* yb      = (u16*)(ws + 32 * MB);   //  8 MB  [4096][1024] bf16
  float* x1    = (float*)(ws + 40 * MB); // 16 MB  [4096][1024] f32
  u16* h2      = (u16*)(ws + 56 * MB);   //  8 MB
  u16* hf      = (u16*)(ws + 64 * MB);   // 32 MB  [4096][4096] bf16
  u16* wattnT  = (u16*)(ws + 96 * MB);   //  6 MB  [3072][1024]
  u16* wprojT  = (u16*)(ws + 102 * MB);  //  2 MB  [1024][1024]
  u16* wfcT    = (u16*)(ws + 104 * MB);  //  8 MB  [4096][1024]
  u16* wcprojT = (u16*)(ws + 112 * MB);  //  8 MB  [1024][4096]

  convT<<<dim3(16, 48), 256, 0, stream>>>(wattn, wattnT, 1024, 3072);
  convT<<<dim3(16, 16), 256, 0, stream>>>(wproj, wprojT, 1024, 1024);
  convT<<<dim3(16, 64), 256, 0, stream>>>(wfc, wfcT, 1024, 4096);
  convT<<<dim3(64, 16), 256, 0, stream>>>(wcproj, wcprojT, 4096, 1024);

  ln_bf16<<<4096, 256, 0, stream>>>(x, ln1w, h1);
  gemm128<0><<<dim3(24, 32, 1), 256, 0, stream>>>(h1, wattnT, qkvb, 4096, 3072, 1024);
  attn_fwd<<<dim3(16, 32), 256, 0, stream>>>(qkvb, yb);
  fill_f32<<<4096, 256, 0, stream>>>(x, x1, 1024 * 1024);
  gemm128<3><<<dim3(8, 32, 2), 256, 0, stream>>>(yb, wprojT, x1, 4096, 1024, 1024);
  ln_bf16<<<4096, 256, 0, stream>>>(x1, ln2w, h2);
  gemm128<2><<<dim3(32, 32, 1), 256, 0, stream>>>(h2, wfcT, hf, 4096, 4096, 1024);
  fill_f32<<<4096, 256, 0, stream>>>(x1, out, 1024 * 1024);
  gemm128<3><<<dim3(8, 32, 4), 256, 0, stream>>>(hf, wcprojT, out, 4096, 1024, 4096);
}

// Round 7
// 276.389 us; speedup vs baseline: 1.8227x; 1.1686x over previous
//
#include <hip/hip_runtime.h>

typedef __attribute__((ext_vector_type(8))) __bf16 bf16x8;
typedef __attribute__((ext_vector_type(4))) float f32x4;
typedef __attribute__((ext_vector_type(8))) unsigned short u16x8;
typedef unsigned short u16;

__device__ __forceinline__ u16 f2bf(float f) {
  unsigned u = __builtin_bit_cast(unsigned, f);
  u = u + 0x7FFFu + ((u >> 16) & 1u);
  return (u16)(u >> 16);
}
__device__ __forceinline__ float bf2f(u16 u) {
  return __builtin_bit_cast(float, ((unsigned)u) << 16);
}

__device__ __forceinline__ f32x4 mfma16(bf16x8 a, bf16x8 b, f32x4 c) {
  return __builtin_amdgcn_mfma_f32_16x16x32_bf16(a, b, c, 0, 0, 0);
}

__device__ __forceinline__ void gl_lds16(const void* g, void* l) {
  __builtin_amdgcn_global_load_lds(
      (const __attribute__((address_space(1))) unsigned int*)g,
      (__attribute__((address_space(3))) unsigned int*)l, 16, 0, 0);
}

// ---------------- coalesced tiled transpose+convert: out[n][k] = bf16(in[k][n]) ------
__global__ __launch_bounds__(256) void convT(const float* __restrict__ in,
                                             u16* __restrict__ outT, int K, int N) {
  __shared__ float tile[64][65];
  const int t = threadIdx.x;
  const int tk = blockIdx.x * 64, tn = blockIdx.y * 64;
  const int lk = t >> 4, ln = (t & 15) * 4;
#pragma unroll
  for (int r = 0; r < 4; ++r) {
    const int k = lk + r * 16;
    const float4 v = *(const float4*)(in + (size_t)(tk + k) * N + tn + ln);
    tile[k][ln + 0] = v.x; tile[k][ln + 1] = v.y;
    tile[k][ln + 2] = v.z; tile[k][ln + 3] = v.w;
  }
  __syncthreads();
  const int sn = t >> 2, sk = (t & 3) * 4;
#pragma unroll
  for (int j = 0; j < 4; ++j) {
    const int k = sk + j * 16;
    ushort4 o;
    o.x = f2bf(tile[k + 0][sn]); o.y = f2bf(tile[k + 1][sn]);
    o.z = f2bf(tile[k + 2][sn]); o.w = f2bf(tile[k + 3][sn]);
    *(ushort4*)(outT + (size_t)(tn + sn) * K + tk + k) = o;
  }
}

// ---------------- LayerNorm (C=1024 fixed), fp32 in -> bf16 out ----------------------
__global__ __launch_bounds__(256) void ln_bf16(const float* __restrict__ x,
                                               const float* __restrict__ wgt,
                                               u16* __restrict__ out) {
  const int row = blockIdx.x, t = threadIdx.x;
  const float4 v = ((const float4*)(x + (size_t)row * 1024))[t];
  float s = v.x + v.y + v.z + v.w;
  float q = v.x * v.x + v.y * v.y + v.z * v.z + v.w * v.w;
#pragma unroll
  for (int d = 32; d; d >>= 1) { s += __shfl_xor(s, d); q += __shfl_xor(q, d); }
  __shared__ float sb[8];
  const int wv = t >> 6;
  if ((t & 63) == 0) { sb[wv] = s; sb[4 + wv] = q; }
  __syncthreads();
  s = sb[0] + sb[1] + sb[2] + sb[3];
  q = sb[4] + sb[5] + sb[6] + sb[7];
  const float mu = s * (1.f / 1024.f);
  const float rstd = rsqrtf(q * (1.f / 1024.f) - mu * mu + 1e-5f);
  const float4 w4 = ((const float4*)wgt)[t];
  ushort4 o;
  o.x = f2bf((v.x - mu) * rstd * w4.x);
  o.y = f2bf((v.y - mu) * rstd * w4.y);
  o.z = f2bf((v.z - mu) * rstd * w4.z);
  o.w = f2bf((v.w - mu) * rstd * w4.w);
  *(ushort4*)(out + (size_t)row * 1024 + t * 4) = o;
}

// ---- reduce_ln: x1 = x + sum(bf16 partials); h2 = LN(x1)*w. one block per row -------
__global__ __launch_bounds__(256) void reduce_ln(const float* __restrict__ x,
                                                 const u16* __restrict__ p, int nseg,
                                                 const float* __restrict__ wgt,
                                                 float* __restrict__ x1,
                                                 u16* __restrict__ h2) {
  const int row = blockIdx.x, t = threadIdx.x;
  const size_t ro = (size_t)row * 1024 + t * 4;
  float4 v = *(const float4*)(x + ro);
  for (int sgm = 0; sgm < nseg; ++sgm) {
    const ushort4 u = *(const ushort4*)(p + (size_t)sgm * 4096 * 1024 + ro);
    v.x += bf2f(u.x); v.y += bf2f(u.y); v.z += bf2f(u.z); v.w += bf2f(u.w);
  }
  *(float4*)(x1 + ro) = v;
  float s = v.x + v.y + v.z + v.w;
  float q = v.x * v.x + v.y * v.y + v.z * v.z + v.w * v.w;
#pragma unroll
  for (int d = 32; d; d >>= 1) { s += __shfl_xor(s, d); q += __shfl_xor(q, d); }
  __shared__ float sb[8];
  const int wv = t >> 6;
  if ((t & 63) == 0) { sb[wv] = s; sb[4 + wv] = q; }
  __syncthreads();
  s = sb[0] + sb[1] + sb[2] + sb[3];
  q = sb[4] + sb[5] + sb[6] + sb[7];
  const float mu = s * (1.f / 1024.f);
  const float rstd = rsqrtf(q * (1.f / 1024.f) - mu * mu + 1e-5f);
  const float4 w4 = ((const float4*)wgt)[t];
  ushort4 o;
  o.x = f2bf((v.x - mu) * rstd * w4.x);
  o.y = f2bf((v.y - mu) * rstd * w4.y);
  o.z = f2bf((v.z - mu) * rstd * w4.z);
  o.w = f2bf((v.w - mu) * rstd * w4.w);
  *(ushort4*)(h2 + ro) = o;
}

// ---- reduce_out: out = x1 + sum(bf16 partials). one float4 per thread ---------------
__global__ __launch_bounds__(256) void reduce_out(const float* __restrict__ x1,
                                                  const u16* __restrict__ p, int nseg,
                                                  float* __restrict__ out) {
  const int i = blockIdx.x * blockDim.x + threadIdx.x;
  const size_t ro = (size_t)i * 4;
  float4 v = *(const float4*)(x1 + ro);
  for (int sgm = 0; sgm < nseg; ++sgm) {
    const ushort4 u = *(const ushort4*)(p + (size_t)sgm * 4096 * 1024 + ro);
    v.x += bf2f(u.x); v.y += bf2f(u.y); v.z += bf2f(u.z); v.w += bf2f(u.w);
  }
  *(float4*)(out + ro) = v;
}

// ---------------- 128x128 bf16 MFMA GEMM, A[M][K] x Bt[N][K]^T -> out[M][N] ----------
// 2-phase double-buffered staging; split-K partials via gridDim.z; XCD-swizzled ids.
// EPI 0: bf16 = acc ; EPI 2: bf16 = relu(acc) ; EPI 4: bf16 partial at seg bz
template <int EPI>
__global__ __launch_bounds__(256) void gemm128(const u16* __restrict__ A,
                                               const u16* __restrict__ Bt,
                                               void* __restrict__ outp,
                                               int M, int N, int K) {
  __shared__ u16 As[2][4096];  // [128][32]
  __shared__ u16 Bs[2][4096];  // [128 n][32 k]
  // XCD-aware bijective swizzle on the full flat id (all grids are %8 == 0)
  const unsigned gx = gridDim.x, gy = gridDim.y, gxy = gx * gy;
  const unsigned nwg = gxy * gridDim.z;
  unsigned f = (blockIdx.z * gy + blockIdx.y) * gx + blockIdx.x;
  if ((nwg & 7u) == 0u) { const unsigned qq = nwg >> 3; f = (f & 7u) * qq + (f >> 3); }
  const int bx = f % gx, by = (f / gx) % gy, bz = f / gxy;

  const int t = threadIdx.x, w = t >> 6, l = t & 63;
  const int lr = l & 15, g = l >> 4;
  const int row0 = by * 128, col0 = bx * 128;
  const int segK = K / gridDim.z;
  const int k0 = bz * segK, kend = k0 + segK;
  const int wr = w >> 1, wc = w & 1;
  f32x4 acc[4][4] = {};

  const int sr = t >> 2;        // staging row 0..63
  const int sk = (t & 3) << 3;  // staging k-offset
  const u16* Ag = A + (size_t)(row0 + sr) * K + sk;
  const u16* Bg = Bt + (size_t)(col0 + sr) * K + sk;
  const size_t rstride = (size_t)64 * K;

  auto stage = [&](int kt, int bb) {
    u16* AsW = As[bb] + w * 512;
    u16* BsW = Bs[bb] + w * 512;
    gl_lds16(Ag + kt, AsW);
    gl_lds16(Ag + kt + rstride, AsW + 2048);
    gl_lds16(Bg + kt, BsW);
    gl_lds16(Bg + kt + rstride, BsW + 2048);
  };

  stage(k0, 0);
  __syncthreads();
  int cur = 0;
  for (int kt = k0; kt < kend; kt += 32) {
    if (kt + 32 < kend) stage(kt + 32, cur ^ 1);
    bf16x8 af[4], bfr[4];
#pragma unroll
    for (int m = 0; m < 4; ++m)
      af[m] = *(const bf16x8*)(As[cur] + (wr * 64 + m * 16 + lr) * 32 + g * 8);
#pragma unroll
    for (int n = 0; n < 4; ++n)
      bfr[n] = *(const bf16x8*)(Bs[cur] + (wc * 64 + n * 16 + lr) * 32 + g * 8);
#pragma unroll
    for (int m = 0; m < 4; ++m)
#pragma unroll
      for (int n = 0; n < 4; ++n) acc[m][n] = mfma16(af[m], bfr[n], acc[m][n]);
    __syncthreads();
    cur ^= 1;
  }

  const size_t segoff = (size_t)bz * M * N;
#pragma unroll
  for (int m = 0; m < 4; ++m)
#pragma unroll
    for (int n = 0; n < 4; ++n)
#pragma unroll
      for (int r = 0; r < 4; ++r) {
        const int row = row0 + wr * 64 + m * 16 + g * 4 + r;
        const int col = col0 + wc * 64 + n * 16 + lr;
        const size_t idx = (size_t)row * N + col;
        const float v = acc[m][n][r];
        if constexpr (EPI == 0) ((u16*)outp)[idx] = f2bf(v);
        else if constexpr (EPI == 2) ((u16*)outp)[idx] = f2bf(fmaxf(v, 0.f));
        else ((u16*)outp)[segoff + idx] = f2bf(v);
      }
}

// ---------------- causal flash attention, bf16 MFMA (R4-verified) --------------------
__global__ __launch_bounds__(256) void attn_fwd(const u16* __restrict__ qkvb,
                                                u16* __restrict__ y) {
  __shared__ u16 Ks[2][4096];      // 2 x 8KB
  __shared__ u16 Vt[2][64 * 80];   // 2 x 10KB, [dh][kv] stride 80
  __shared__ u16 Pb[4][16 * 72];   // per-wave P: [q 0..15][kv 0..63], stride 72
  const int t = threadIdx.x, w = t >> 6, l = t & 63;
  const int lr = l & 15, g = l >> 4;
  const int bh = blockIdx.y, b = bh >> 4, h = bh & 15;
  const size_t base = (size_t)b * 2048 * 3072;
  const u16* Kg = qkvb + base + 1024 + h * 64;
  const u16* Vg = qkvb + base + 2048 + h * 64;
  u16* Pw = &Pb[w][0];
  const int vkv = t & 63;          // V staging: kv row
  const int vd0 = (t >> 6) * 16;   // V staging: dh chunk base

  auto stageK = [&](int kv0, int bb) {
#pragma unroll
    for (int r = 0; r < 2; ++r) {
      const int dl = (r * 256 + t) * 16;                  // dest byte in 8KB tile
      const int row = dl >> 7;
      const int srcb = (dl & 127) ^ ((row & 7) << 4);     // inverse-swizzled source
      gl_lds16(Kg + (size_t)(kv0 + row) * 3072 + (srcb >> 1),
               (char*)Ks[bb] + r * 4096 + w * 1024);
    }
  };

  for (int pass = 0; pass < 2; ++pass) {
    const int qt = (pass == 0) ? blockIdx.x : 31 - blockIdx.x;
    const int q0 = qt * 64, q0w = q0 + w * 16, nt = qt + 1;
    const u16* Qp = qkvb + base + (size_t)(q0w + lr) * 3072 + h * 64;
    const bf16x8 qf0 = *(const bf16x8*)(Qp + g * 8);
    const bf16x8 qf1 = *(const bf16x8*)(Qp + 32 + g * 8);
    f32x4 o[4] = {};
    float m_run[4] = {-1e30f, -1e30f, -1e30f, -1e30f};
    float s_lane[4] = {0.f, 0.f, 0.f, 0.f};

    stageK(0, 0);
    u16x8 v0 = *(const u16x8*)(Vg + (size_t)vkv * 3072 + vd0);
    u16x8 v1 = *(const u16x8*)(Vg + (size_t)vkv * 3072 + vd0 + 8);
#pragma unroll
    for (int j = 0; j < 8; ++j) {
      Vt[0][(vd0 + j) * 80 + vkv] = v0[j];
      Vt[0][(vd0 + 8 + j) * 80 + vkv] = v1[j];
    }
    __syncthreads();

    int ct = 0;
    for (int tt = 0; tt < nt; ++tt) {
      const int kv0 = tt * 64;
      const bool more = (tt + 1 < nt);
      if (more) {  // issue next-tile staging early (T14)
        stageK(kv0 + 64, ct ^ 1);
        v0 = *(const u16x8*)(Vg + (size_t)(kv0 + 64 + vkv) * 3072 + vd0);
        v1 = *(const u16x8*)(Vg + (size_t)(kv0 + 64 + vkv) * 3072 + vd0 + 8);
      }

      const u16* Kbuf = Ks[ct];
      f32x4 s4[4];
#pragma unroll
      for (int i = 0; i < 4; ++i) {
        const int row = i * 16 + lr;
        const int sw = (row & 7) << 4;
        const bf16x8 k0 = *(const bf16x8*)(Kbuf + row * 64 + (((g * 16) ^ sw) >> 1));
        const bf16x8 k1 = *(const bf16x8*)(Kbuf + row * 64 + (((64 + g * 16) ^ sw) >> 1));
        f32x4 z = {0.f, 0.f, 0.f, 0.f};
        z = mfma16(qf0, k0, z);
        z = mfma16(qf1, k1, z);
        s4[i] = z * 0.03125f;  // * C^-0.5 = 1/32 (full embed dim, per reference)
      }
      if (kv0 + 64 > q0w) {  // causal mask (diagonal tile only)
#pragma unroll
        for (int i = 0; i < 4; ++i) {
          const int col = kv0 + i * 16 + lr;
#pragma unroll
          for (int r = 0; r < 4; ++r)
            if (col > q0w + g * 4 + r) s4[i][r] = -1e30f;
        }
      }
#pragma unroll
      for (int r = 0; r < 4; ++r) {
        float mx = fmaxf(fmaxf(s4[0][r], s4[1][r]), fmaxf(s4[2][r], s4[3][r]));
        mx = fmaxf(mx, __shfl_xor(mx, 1));
        mx = fmaxf(mx, __shfl_xor(mx, 2));
        mx = fmaxf(mx, __shfl_xor(mx, 4));
        mx = fmaxf(mx, __shfl_xor(mx, 8));
        const float mnew = fmaxf(m_run[r], mx);
        const float sc = __expf(m_run[r] - mnew);
        m_run[r] = mnew;
        const float p0 = __expf(s4[0][r] - mnew), p1 = __expf(s4[1][r] - mnew);
        const float p2 = __expf(s4[2][r] - mnew), p3 = __expf(s4[3][r] - mnew);
        s_lane[r] = s_lane[r] * sc + (p0 + p1) + (p2 + p3);  // deferred denominator
        o[0][r] *= sc; o[1][r] *= sc; o[2][r] *= sc; o[3][r] *= sc;
        const int pr = (g * 4 + r) * 72 + lr;
        Pw[pr] = f2bf(p0); Pw[pr + 16] = f2bf(p1);
        Pw[pr + 32] = f2bf(p2); Pw[pr + 48] = f2bf(p3);
      }
#pragma unroll
      for (int s = 0; s < 2; ++s) {
        const bf16x8 pa = *(const bf16x8*)(Pw + lr * 72 + s * 32 + g * 8);
#pragma unroll
        for (int n = 0; n < 4; ++n) {
          const bf16x8 vf =
              *(const bf16x8*)(&Vt[ct][(n * 16 + lr) * 80 + s * 32 + g * 8]);
          o[n] = mfma16(pa, vf, o[n]);
        }
      }
      if (more) {
#pragma unroll
        for (int j = 0; j < 8; ++j) {
          Vt[ct ^ 1][(vd0 + j) * 80 + vkv] = v0[j];
          Vt[ct ^ 1][(vd0 + 8 + j) * 80 + vkv] = v1[j];
        }
      }
      __syncthreads();
      ct ^= 1;
    }

    float inv[4];
#pragma unroll
    for (int r = 0; r < 4; ++r) {
      float den = s_lane[r];
      den += __shfl_xor(den, 1);
      den += __shfl_xor(den, 2);
      den += __shfl_xor(den, 4);
      den += __shfl_xor(den, 8);
      inv[r] = 1.f / den;
    }
#pragma unroll
    for (int n = 0; n < 4; ++n)
#pragma unroll
      for (int r = 0; r < 4; ++r) {
        const int row = q0w + g * 4 + r;
        const int col = h * 64 + n * 16 + lr;
        y[(size_t)(b * 2048 + row) * 1024 + col] = f2bf(o[n][r] * inv[r]);
      }
  }
}

// ------------------------------------------------------------------------------------
// ws layout (MB), peak 120 (proven footprint):
//   0..24  qkvb            (qkv gemm -> attn)          | later cprojP 0..32
//  24..32  h1 (ln1 -> qkv) | later yb (attn -> proj)
//  32..48  projP (2 x 8MB bf16 partials)
//  48..64  x1 (f32)
//  64..72  h2
//  72..104 hf
// 104..112 wattnT(6)+wprojT(2) -> later wcprojT(8) (converted after proj gemm)
// 112..120 wfcT
extern "C" void kernel_launch(void* const* d_in, const int* in_sizes, int n_in,
                              void* d_out, int out_size, void* d_ws, size_t ws_size,
                              hipStream_t stream) {
  const float* x      = (const float*)d_in[0];
  const float* ln1w   = (const float*)d_in[1];
  const float* wattn  = (const float*)d_in[2];
  const float* wproj  = (const float*)d_in[3];
  const float* ln2w   = (const float*)d_in[4];
  const float* wfc    = (const float*)d_in[5];
  const float* wcproj = (const float*)d_in[6];
  float* out = (float*)d_out;
  char* ws = (char*)d_ws;
  const size_t MB = 1024 * 1024;
  u16* qkvb    = (u16*)(ws + 0);
  u16* cprojP  = (u16*)(ws + 0);
  u16* h1      = (u16*)(ws + 24 * MB);
  u16* yb      = (u16*)(ws + 24 * MB);
  u16* projP   = (u16*)(ws + 32 * MB);
  float* x1    = (float*)(ws + 48 * MB);
  u16* h2      = (u16*)(ws + 64 * MB);
  u16* hf      = (u16*)(ws + 72 * MB);
  u16* wattnT  = (u16*)(ws + 104 * MB);
  u16* wprojT  = (u16*)(ws + 110 * MB);
  u16* wcprojT = (u16*)(ws + 104 * MB);
  u16* wfcT    = (u16*)(ws + 112 * MB);

  convT<<<dim3(16, 48), 256, 0, stream>>>(wattn, wattnT, 1024, 3072);
  convT<<<dim3(16, 16), 256, 0, stream>>>(wproj, wprojT, 1024, 1024);
  convT<<<dim3(16, 64), 256, 0, stream>>>(wfc, wfcT, 1024, 4096);

  ln_bf16<<<4096, 256, 0, stream>>>(x, ln1w, h1);
  gemm128<0><<<dim3(24, 32, 1), 256, 0, stream>>>(h1, wattnT, qkvb, 4096, 3072, 1024);
  attn_fwd<<<dim3(16, 32), 256, 0, stream>>>(qkvb, yb);
  gemm128<4><<<dim3(8, 32, 2), 256, 0, stream>>>(yb, wprojT, projP, 4096, 1024, 1024);
  convT<<<dim3(64, 16), 256, 0, stream>>>(wcproj, wcprojT, 4096, 1024);
  reduce_ln<<<4096, 256, 0, stream>>>(x, projP, 2, ln2w, x1, h2);
  gemm128<2><<<dim3(32, 32, 1), 256, 0, stream>>>(h2, wfcT, hf, 4096, 4096, 1024);
  gemm128<4><<<dim3(8, 32, 4), 256, 0, stream>>>(hf, wcprojT, cprojP, 4096, 1024, 4096);
  reduce_out<<<4096, 256, 0, stream>>>(x1, cprojP, 4, out);
}

// Round 8
// 266.297 us; speedup vs baseline: 1.8918x; 1.0379x over previous
//
#include <hip/hip_runtime.h>

typedef __attribute__((ext_vector_type(8))) __bf16 bf16x8;
typedef __attribute__((ext_vector_type(4))) float f32x4;
typedef __attribute__((ext_vector_type(8))) unsigned short u16x8;
typedef unsigned short u16;

__device__ __forceinline__ u16 f2bf(float f) {
  return __builtin_bit_cast(u16, (__bf16)f);  // v_cvt_pk_bf16_f32 (RTNE)
}
__device__ __forceinline__ float bf2f(u16 u) {
  return __builtin_bit_cast(float, ((unsigned)u) << 16);
}

__device__ __forceinline__ f32x4 mfma16(bf16x8 a, bf16x8 b, f32x4 c) {
  return __builtin_amdgcn_mfma_f32_16x16x32_bf16(a, b, c, 0, 0, 0);
}

__device__ __forceinline__ void gl_lds16(const void* g, void* l) {
  __builtin_amdgcn_global_load_lds(
      (const __attribute__((address_space(1))) unsigned int*)g,
      (__attribute__((address_space(3))) unsigned int*)l, 16, 0, 0);
}

// ---------------- coalesced tiled transpose+convert: out[n][k] = bf16(in[k][n]) ------
__global__ __launch_bounds__(256) void convT(const float* __restrict__ in,
                                             u16* __restrict__ outT, int K, int N) {
  __shared__ float tile[64][65];
  const int t = threadIdx.x;
  const int tk = blockIdx.x * 64, tn = blockIdx.y * 64;
  const int lk = t >> 4, ln = (t & 15) * 4;
#pragma unroll
  for (int r = 0; r < 4; ++r) {
    const int k = lk + r * 16;
    const float4 v = *(const float4*)(in + (size_t)(tk + k) * N + tn + ln);
    tile[k][ln + 0] = v.x; tile[k][ln + 1] = v.y;
    tile[k][ln + 2] = v.z; tile[k][ln + 3] = v.w;
  }
  __syncthreads();
  const int sn = t >> 2, sk = (t & 3) * 4;
#pragma unroll
  for (int j = 0; j < 4; ++j) {
    const int k = sk + j * 16;
    ushort4 o;
    o.x = f2bf(tile[k + 0][sn]); o.y = f2bf(tile[k + 1][sn]);
    o.z = f2bf(tile[k + 2][sn]); o.w = f2bf(tile[k + 3][sn]);
    *(ushort4*)(outT + (size_t)(tn + sn) * K + tk + k) = o;
  }
}

// ---------------- LayerNorm (C=1024 fixed), fp32 in -> bf16 out ----------------------
__global__ __launch_bounds__(256) void ln_bf16(const float* __restrict__ x,
                                               const float* __restrict__ wgt,
                                               u16* __restrict__ out) {
  const int row = blockIdx.x, t = threadIdx.x;
  const float4 v = ((const float4*)(x + (size_t)row * 1024))[t];
  float s = v.x + v.y + v.z + v.w;
  float q = v.x * v.x + v.y * v.y + v.z * v.z + v.w * v.w;
#pragma unroll
  for (int d = 32; d; d >>= 1) { s += __shfl_xor(s, d); q += __shfl_xor(q, d); }
  __shared__ float sb[8];
  const int wv = t >> 6;
  if ((t & 63) == 0) { sb[wv] = s; sb[4 + wv] = q; }
  __syncthreads();
  s = sb[0] + sb[1] + sb[2] + sb[3];
  q = sb[4] + sb[5] + sb[6] + sb[7];
  const float mu = s * (1.f / 1024.f);
  const float rstd = rsqrtf(q * (1.f / 1024.f) - mu * mu + 1e-5f);
  const float4 w4 = ((const float4*)wgt)[t];
  ushort4 o;
  o.x = f2bf((v.x - mu) * rstd * w4.x);
  o.y = f2bf((v.y - mu) * rstd * w4.y);
  o.z = f2bf((v.z - mu) * rstd * w4.z);
  o.w = f2bf((v.w - mu) * rstd * w4.w);
  *(ushort4*)(out + (size_t)row * 1024 + t * 4) = o;
}

// ---- reduce_ln: x1 = x + sum(bf16 partials); h2 = LN(x1)*w. one block per row -------
__global__ __launch_bounds__(256) void reduce_ln(const float* __restrict__ x,
                                                 const u16* __restrict__ p, int nseg,
                                                 const float* __restrict__ wgt,
                                                 float* __restrict__ x1,
                                                 u16* __restrict__ h2) {
  const int row = blockIdx.x, t = threadIdx.x;
  const size_t ro = (size_t)row * 1024 + t * 4;
  float4 v = *(const float4*)(x + ro);
  for (int sgm = 0; sgm < nseg; ++sgm) {
    const ushort4 u = *(const ushort4*)(p + (size_t)sgm * 4096 * 1024 + ro);
    v.x += bf2f(u.x); v.y += bf2f(u.y); v.z += bf2f(u.z); v.w += bf2f(u.w);
  }
  *(float4*)(x1 + ro) = v;
  float s = v.x + v.y + v.z + v.w;
  float q = v.x * v.x + v.y * v.y + v.z * v.z + v.w * v.w;
#pragma unroll
  for (int d = 32; d; d >>= 1) { s += __shfl_xor(s, d); q += __shfl_xor(q, d); }
  __shared__ float sb[8];
  const int wv = t >> 6;
  if ((t & 63) == 0) { sb[wv] = s; sb[4 + wv] = q; }
  __syncthreads();
  s = sb[0] + sb[1] + sb[2] + sb[3];
  q = sb[4] + sb[5] + sb[6] + sb[7];
  const float mu = s * (1.f / 1024.f);
  const float rstd = rsqrtf(q * (1.f / 1024.f) - mu * mu + 1e-5f);
  const float4 w4 = ((const float4*)wgt)[t];
  ushort4 o;
  o.x = f2bf((v.x - mu) * rstd * w4.x);
  o.y = f2bf((v.y - mu) * rstd * w4.y);
  o.z = f2bf((v.z - mu) * rstd * w4.z);
  o.w = f2bf((v.w - mu) * rstd * w4.w);
  *(ushort4*)(h2 + ro) = o;
}

// ---- reduce_out: out = x1 + sum(bf16 partials). one float4 per thread ---------------
__global__ __launch_bounds__(256) void reduce_out(const float* __restrict__ x1,
                                                  const u16* __restrict__ p, int nseg,
                                                  float* __restrict__ out) {
  const int i = blockIdx.x * blockDim.x + threadIdx.x;
  const size_t ro = (size_t)i * 4;
  float4 v = *(const float4*)(x1 + ro);
  for (int sgm = 0; sgm < nseg; ++sgm) {
    const ushort4 u = *(const ushort4*)(p + (size_t)sgm * 4096 * 1024 + ro);
    v.x += bf2f(u.x); v.y += bf2f(u.y); v.z += bf2f(u.z); v.w += bf2f(u.w);
  }
  *(float4*)(out + ro) = v;
}

// ---------------- 128x128 bf16 MFMA GEMM, A[M][K] x Bt[N][K]^T -> out[M][N] ----------
// 2-phase double-buffered staging; split-K partials via gridDim.z; XCD-swizzled ids.
// EPI 0: bf16 = acc ; EPI 2: bf16 = relu(acc) ; EPI 4: bf16 partial at seg bz
template <int EPI>
__global__ __launch_bounds__(256) void gemm128(const u16* __restrict__ A,
                                               const u16* __restrict__ Bt,
                                               void* __restrict__ outp,
                                               int M, int N, int K) {
  __shared__ u16 As[2][4096];  // [128][32]
  __shared__ u16 Bs[2][4096];  // [128 n][32 k]
  // XCD-aware bijective swizzle on the full flat id (all grids are %8 == 0)
  const unsigned gx = gridDim.x, gy = gridDim.y, gxy = gx * gy;
  const unsigned nwg = gxy * gridDim.z;
  unsigned f = (blockIdx.z * gy + blockIdx.y) * gx + blockIdx.x;
  if ((nwg & 7u) == 0u) { const unsigned qq = nwg >> 3; f = (f & 7u) * qq + (f >> 3); }
  const int bx = f % gx, by = (f / gx) % gy, bz = f / gxy;

  const int t = threadIdx.x, w = t >> 6, l = t & 63;
  const int lr = l & 15, g = l >> 4;
  const int row0 = by * 128, col0 = bx * 128;
  const int segK = K / gridDim.z;
  const int k0 = bz * segK, kend = k0 + segK;
  const int wr = w >> 1, wc = w & 1;
  f32x4 acc[4][4] = {};

  const int sr = t >> 2;        // staging row 0..63
  const int sk = (t & 3) << 3;  // staging k-offset
  const u16* Ag = A + (size_t)(row0 + sr) * K + sk;
  const u16* Bg = Bt + (size_t)(col0 + sr) * K + sk;
  const size_t rstride = (size_t)64 * K;

  auto stage = [&](int kt, int bb) {
    u16* AsW = As[bb] + w * 512;
    u16* BsW = Bs[bb] + w * 512;
    gl_lds16(Ag + kt, AsW);
    gl_lds16(Ag + kt + rstride, AsW + 2048);
    gl_lds16(Bg + kt, BsW);
    gl_lds16(Bg + kt + rstride, BsW + 2048);
  };

  stage(k0, 0);
  __syncthreads();
  int cur = 0;
  for (int kt = k0; kt < kend; kt += 32) {
    if (kt + 32 < kend) stage(kt + 32, cur ^ 1);
    bf16x8 af[4], bfr[4];
#pragma unroll
    for (int m = 0; m < 4; ++m)
      af[m] = *(const bf16x8*)(As[cur] + (wr * 64 + m * 16 + lr) * 32 + g * 8);
#pragma unroll
    for (int n = 0; n < 4; ++n)
      bfr[n] = *(const bf16x8*)(Bs[cur] + (wc * 64 + n * 16 + lr) * 32 + g * 8);
#pragma unroll
    for (int m = 0; m < 4; ++m)
#pragma unroll
      for (int n = 0; n < 4; ++n) acc[m][n] = mfma16(af[m], bfr[n], acc[m][n]);
    __syncthreads();
    cur ^= 1;
  }

  const size_t segoff = (size_t)bz * M * N;
#pragma unroll
  for (int m = 0; m < 4; ++m)
#pragma unroll
    for (int n = 0; n < 4; ++n)
#pragma unroll
      for (int r = 0; r < 4; ++r) {
        const int row = row0 + wr * 64 + m * 16 + g * 4 + r;
        const int col = col0 + wc * 64 + n * 16 + lr;
        const size_t idx = (size_t)row * N + col;
        const float v = acc[m][n][r];
        if constexpr (EPI == 0) ((u16*)outp)[idx] = f2bf(v);
        else if constexpr (EPI == 2) ((u16*)outp)[idx] = f2bf(fmaxf(v, 0.f));
        else ((u16*)outp)[segoff + idx] = f2bf(v);
      }
}

// ---------------- causal flash attention, bf16 MFMA ---------------------------------
// One q-tile (64 rows) per block, grid 1024 blocks. Flat-id remap groups all q-tiles
// of one (b,h) onto ONE XCD (L2-resident K/V) and dispatches large-qt blocks first.
// Inner loop identical to the R4/R7-verified kernel.
__global__ __launch_bounds__(256) void attn_fwd(const u16* __restrict__ qkvb,
                                                u16* __restrict__ y) {
  __shared__ u16 Ks[2][4096];      // 2 x 8KB
  __shared__ u16 Vt[2][64 * 80];   // 2 x 10KB, [dh][kv] stride 80
  __shared__ u16 Pb[4][16 * 72];   // per-wave P: [q 0..15][kv 0..63], stride 72
  const int t = threadIdx.x, w = t >> 6, l = t & 63;
  const int lr = l & 15, g = l >> 4;
  // remap: xcd = f&7 (round-robin heuristic); bh = xcd + 8*(j&3) -> bh&7 == xcd;
  // qt descending in dispatch order so long blocks start first.
  const unsigned f = blockIdx.y * gridDim.x + blockIdx.x;
  const int xcd = f & 7, j = f >> 3;
  const int bh = xcd + 8 * (j & 3);
  const int qt = 31 - (j >> 2);
  const int b = bh >> 4, h = bh & 15;
  const size_t base = (size_t)b * 2048 * 3072;
  const u16* Kg = qkvb + base + 1024 + h * 64;
  const u16* Vg = qkvb + base + 2048 + h * 64;
  u16* Pw = &Pb[w][0];
  const int vkv = t & 63;          // V staging: kv row
  const int vd0 = (t >> 6) * 16;   // V staging: dh chunk base

  auto stageK = [&](int kv0, int bb) {
#pragma unroll
    for (int r = 0; r < 2; ++r) {
      const int dl = (r * 256 + t) * 16;                  // dest byte in 8KB tile
      const int row = dl >> 7;
      const int srcb = (dl & 127) ^ ((row & 7) << 4);     // inverse-swizzled source
      gl_lds16(Kg + (size_t)(kv0 + row) * 3072 + (srcb >> 1),
               (char*)Ks[bb] + r * 4096 + w * 1024);
    }
  };

  const int q0 = qt * 64, q0w = q0 + w * 16, nt = qt + 1;
  const u16* Qp = qkvb + base + (size_t)(q0w + lr) * 3072 + h * 64;
  const bf16x8 qf0 = *(const bf16x8*)(Qp + g * 8);
  const bf16x8 qf1 = *(const bf16x8*)(Qp + 32 + g * 8);
  f32x4 o[4] = {};
  float m_run[4] = {-1e30f, -1e30f, -1e30f, -1e30f};
  float s_lane[4] = {0.f, 0.f, 0.f, 0.f};

  stageK(0, 0);
  u16x8 v0 = *(const u16x8*)(Vg + (size_t)vkv * 3072 + vd0);
  u16x8 v1 = *(const u16x8*)(Vg + (size_t)vkv * 3072 + vd0 + 8);
#pragma unroll
  for (int jj = 0; jj < 8; ++jj) {
    Vt[0][(vd0 + jj) * 80 + vkv] = v0[jj];
    Vt[0][(vd0 + 8 + jj) * 80 + vkv] = v1[jj];
  }
  __syncthreads();

  int ct = 0;
  for (int tt = 0; tt < nt; ++tt) {
    const int kv0 = tt * 64;
    const bool more = (tt + 1 < nt);
    if (more) {  // issue next-tile staging early (T14)
      stageK(kv0 + 64, ct ^ 1);
      v0 = *(const u16x8*)(Vg + (size_t)(kv0 + 64 + vkv) * 3072 + vd0);
      v1 = *(const u16x8*)(Vg + (size_t)(kv0 + 64 + vkv) * 3072 + vd0 + 8);
    }

    const u16* Kbuf = Ks[ct];
    f32x4 s4[4];
#pragma unroll
    for (int i = 0; i < 4; ++i) {
      const int row = i * 16 + lr;
      const int sw = (row & 7) << 4;
      const bf16x8 k0 = *(const bf16x8*)(Kbuf + row * 64 + (((g * 16) ^ sw) >> 1));
      const bf16x8 k1 = *(const bf16x8*)(Kbuf + row * 64 + (((64 + g * 16) ^ sw) >> 1));
      f32x4 z = {0.f, 0.f, 0.f, 0.f};
      z = mfma16(qf0, k0, z);
      z = mfma16(qf1, k1, z);
      s4[i] = z * 0.03125f;  // * C^-0.5 = 1/32 (full embed dim, per reference)
    }
    if (kv0 + 64 > q0w) {  // causal mask (diagonal tile only)
#pragma unroll
      for (int i = 0; i < 4; ++i) {
        const int col = kv0 + i * 16 + lr;
#pragma unroll
        for (int r = 0; r < 4; ++r)
          if (col > q0w + g * 4 + r) s4[i][r] = -1e30f;
      }
    }
#pragma unroll
    for (int r = 0; r < 4; ++r) {
      float mx = fmaxf(fmaxf(s4[0][r], s4[1][r]), fmaxf(s4[2][r], s4[3][r]));
      mx = fmaxf(mx, __shfl_xor(mx, 1));
      mx = fmaxf(mx, __shfl_xor(mx, 2));
      mx = fmaxf(mx, __shfl_xor(mx, 4));
      mx = fmaxf(mx, __shfl_xor(mx, 8));
      const float mnew = fmaxf(m_run[r], mx);
      const float sc = __expf(m_run[r] - mnew);
      m_run[r] = mnew;
      const float p0 = __expf(s4[0][r] - mnew), p1 = __expf(s4[1][r] - mnew);
      const float p2 = __expf(s4[2][r] - mnew), p3 = __expf(s4[3][r] - mnew);
      s_lane[r] = s_lane[r] * sc + (p0 + p1) + (p2 + p3);  // deferred denominator
      o[0][r] *= sc; o[1][r] *= sc; o[2][r] *= sc; o[3][r] *= sc;
      const int pr = (g * 4 + r) * 72 + lr;
      Pw[pr] = f2bf(p0); Pw[pr + 16] = f2bf(p1);
      Pw[pr + 32] = f2bf(p2); Pw[pr + 48] = f2bf(p3);
    }
#pragma unroll
    for (int s = 0; s < 2; ++s) {
      const bf16x8 pa = *(const bf16x8*)(Pw + lr * 72 + s * 32 + g * 8);
#pragma unroll
      for (int n = 0; n < 4; ++n) {
        const bf16x8 vf =
            *(const bf16x8*)(&Vt[ct][(n * 16 + lr) * 80 + s * 32 + g * 8]);
        o[n] = mfma16(pa, vf, o[n]);
      }
    }
    if (more) {
#pragma unroll
      for (int jj = 0; jj < 8; ++jj) {
        Vt[ct ^ 1][(vd0 + jj) * 80 + vkv] = v0[jj];
        Vt[ct ^ 1][(vd0 + 8 + jj) * 80 + vkv] = v1[jj];
      }
    }
    __syncthreads();
    ct ^= 1;
  }

  float inv[4];
#pragma unroll
  for (int r = 0; r < 4; ++r) {
    float den = s_lane[r];
    den += __shfl_xor(den, 1);
    den += __shfl_xor(den, 2);
    den += __shfl_xor(den, 4);
    den += __shfl_xor(den, 8);
    inv[r] = 1.f / den;
  }
#pragma unroll
  for (int n = 0; n < 4; ++n)
#pragma unroll
    for (int r = 0; r < 4; ++r) {
      const int row = q0w + g * 4 + r;
      const int col = h * 64 + n * 16 + lr;
      y[(size_t)(b * 2048 + row) * 1024 + col] = f2bf(o[n][r] * inv[r]);
    }
}

// ------------------------------------------------------------------------------------
// ws layout (MB), peak 120:
//   0..24  qkvb | later cprojP 0..32
//  24..32  h1   | later yb
//  32..48  projP (2 x 8MB)
//  48..64  x1 (f32)
//  64..72  h2
//  72..104 hf
// 104..112 wattnT(6)+wprojT(2) -> later wcprojT(8)
// 112..120 wfcT
extern "C" void kernel_launch(void* const* d_in, const int* in_sizes, int n_in,
                              void* d_out, int out_size, void* d_ws, size_t ws_size,
                              hipStream_t stream) {
  const float* x      = (const float*)d_in[0];
  const float* ln1w   = (const float*)d_in[1];
  const float* wattn  = (const float*)d_in[2];
  const float* wproj  = (const float*)d_in[3];
  const float* ln2w   = (const float*)d_in[4];
  const float* wfc    = (const float*)d_in[5];
  const float* wcproj = (const float*)d_in[6];
  float* out = (float*)d_out;
  char* ws = (char*)d_ws;
  const size_t MB = 1024 * 1024;
  u16* qkvb    = (u16*)(ws + 0);
  u16* cprojP  = (u16*)(ws + 0);
  u16* h1      = (u16*)(ws + 24 * MB);
  u16* yb      = (u16*)(ws + 24 * MB);
  u16* projP   = (u16*)(ws + 32 * MB);
  float* x1    = (float*)(ws + 48 * MB);
  u16* h2      = (u16*)(ws + 64 * MB);
  u16* hf      = (u16*)(ws + 72 * MB);
  u16* wattnT  = (u16*)(ws + 104 * MB);
  u16* wprojT  = (u16*)(ws + 110 * MB);
  u16* wcprojT = (u16*)(ws + 104 * MB);
  u16* wfcT    = (u16*)(ws + 112 * MB);

  convT<<<dim3(16, 48), 256, 0, stream>>>(wattn, wattnT, 1024, 3072);
  convT<<<dim3(16, 16), 256, 0, stream>>>(wproj, wprojT, 1024, 1024);
  convT<<<dim3(16, 64), 256, 0, stream>>>(wfc, wfcT, 1024, 4096);

  ln_bf16<<<4096, 256, 0, stream>>>(x, ln1w, h1);
  gemm128<0><<<dim3(24, 32, 1), 256, 0, stream>>>(h1, wattnT, qkvb, 4096, 3072, 1024);
  attn_fwd<<<dim3(32, 32), 256, 0, stream>>>(qkvb, yb);
  gemm128<4><<<dim3(8, 32, 2), 256, 0, stream>>>(yb, wprojT, projP, 4096, 1024, 1024);
  convT<<<dim3(64, 16), 256, 0, stream>>>(wcproj, wcprojT, 4096, 1024);
  reduce_ln<<<4096, 256, 0, stream>>>(x, projP, 2, ln2w, x1, h2);
  gemm128<2><<<dim3(32, 32, 1), 256, 0, stream>>>(h2, wfcT, hf, 4096, 4096, 1024);
  gemm128<4><<<dim3(8, 32, 4), 256, 0, stream>>>(hf, wcprojT, cprojP, 4096, 1024, 4096);
  reduce_out<<<4096, 256, 0, stream>>>(x1, cprojP, 4, out);
}

// Round 9
// 258.671 us; speedup vs baseline: 1.9476x; 1.0295x over previous
//
#include <hip/hip_runtime.h>

typedef __attribute__((ext_vector_type(8))) __bf16 bf16x8;
typedef __attribute__((ext_vector_type(4))) float f32x4;
typedef __attribute__((ext_vector_type(8))) unsigned short u16x8;
typedef __attribute__((ext_vector_type(4))) unsigned short u16x4;
typedef unsigned short u16;

__device__ __forceinline__ u16 f2bf(float f) {
  return __builtin_bit_cast(u16, (__bf16)f);
}
__device__ __forceinline__ float bf2f(u16 u) {
  return __builtin_bit_cast(float, ((unsigned)u) << 16);
}

__device__ __forceinline__ f32x4 mfma16(bf16x8 a, bf16x8 b, f32x4 c) {
  return __builtin_amdgcn_mfma_f32_16x16x32_bf16(a, b, c, 0, 0, 0);
}

__device__ __forceinline__ void gl_lds16(const void* g, void* l) {
  __builtin_amdgcn_global_load_lds(
      (const __attribute__((address_space(1))) unsigned int*)g,
      (__attribute__((address_space(3))) unsigned int*)l, 16, 0, 0);
}

__device__ __forceinline__ f32x4 fmax4(f32x4 a, f32x4 b) {
  f32x4 r;
  r[0] = fmaxf(a[0], b[0]); r[1] = fmaxf(a[1], b[1]);
  r[2] = fmaxf(a[2], b[2]); r[3] = fmaxf(a[3], b[3]);
  return r;
}

// ---------------- coalesced tiled transpose+convert: out[n][k] = bf16(in[k][n]) ------
__global__ __launch_bounds__(256) void convT(const float* __restrict__ in,
                                             u16* __restrict__ outT, int K, int N) {
  __shared__ float tile[64][65];
  const int t = threadIdx.x;
  const int tk = blockIdx.x * 64, tn = blockIdx.y * 64;
  const int lk = t >> 4, ln = (t & 15) * 4;
#pragma unroll
  for (int r = 0; r < 4; ++r) {
    const int k = lk + r * 16;
    const float4 v = *(const float4*)(in + (size_t)(tk + k) * N + tn + ln);
    tile[k][ln + 0] = v.x; tile[k][ln + 1] = v.y;
    tile[k][ln + 2] = v.z; tile[k][ln + 3] = v.w;
  }
  __syncthreads();
  const int sn = t >> 2, sk = (t & 3) * 4;
#pragma unroll
  for (int j = 0; j < 4; ++j) {
    const int k = sk + j * 16;
    ushort4 o;
    o.x = f2bf(tile[k + 0][sn]); o.y = f2bf(tile[k + 1][sn]);
    o.z = f2bf(tile[k + 2][sn]); o.w = f2bf(tile[k + 3][sn]);
    *(ushort4*)(outT + (size_t)(tn + sn) * K + tk + k) = o;
  }
}

// ---------------- LayerNorm (C=1024 fixed), fp32 in -> bf16 out ----------------------
__global__ __launch_bounds__(256) void ln_bf16(const float* __restrict__ x,
                                               const float* __restrict__ wgt,
                                               u16* __restrict__ out) {
  const int row = blockIdx.x, t = threadIdx.x;
  const float4 v = ((const float4*)(x + (size_t)row * 1024))[t];
  float s = v.x + v.y + v.z + v.w;
  float q = v.x * v.x + v.y * v.y + v.z * v.z + v.w * v.w;
#pragma unroll
  for (int d = 32; d; d >>= 1) { s += __shfl_xor(s, d); q += __shfl_xor(q, d); }
  __shared__ float sb[8];
  const int wv = t >> 6;
  if ((t & 63) == 0) { sb[wv] = s; sb[4 + wv] = q; }
  __syncthreads();
  s = sb[0] + sb[1] + sb[2] + sb[3];
  q = sb[4] + sb[5] + sb[6] + sb[7];
  const float mu = s * (1.f / 1024.f);
  const float rstd = rsqrtf(q * (1.f / 1024.f) - mu * mu + 1e-5f);
  const float4 w4 = ((const float4*)wgt)[t];
  ushort4 o;
  o.x = f2bf((v.x - mu) * rstd * w4.x);
  o.y = f2bf((v.y - mu) * rstd * w4.y);
  o.z = f2bf((v.z - mu) * rstd * w4.z);
  o.w = f2bf((v.w - mu) * rstd * w4.w);
  *(ushort4*)(out + (size_t)row * 1024 + t * 4) = o;
}

// ---- reduce_ln: x1 = x + sum(bf16 partials); h2 = LN(x1)*w. one block per row -------
__global__ __launch_bounds__(256) void reduce_ln(const float* __restrict__ x,
                                                 const u16* __restrict__ p, int nseg,
                                                 const float* __restrict__ wgt,
                                                 float* __restrict__ x1,
                                                 u16* __restrict__ h2) {
  const int row = blockIdx.x, t = threadIdx.x;
  const size_t ro = (size_t)row * 1024 + t * 4;
  float4 v = *(const float4*)(x + ro);
  for (int sgm = 0; sgm < nseg; ++sgm) {
    const ushort4 u = *(const ushort4*)(p + (size_t)sgm * 4096 * 1024 + ro);
    v.x += bf2f(u.x); v.y += bf2f(u.y); v.z += bf2f(u.z); v.w += bf2f(u.w);
  }
  *(float4*)(x1 + ro) = v;
  float s = v.x + v.y + v.z + v.w;
  float q = v.x * v.x + v.y * v.y + v.z * v.z + v.w * v.w;
#pragma unroll
  for (int d = 32; d; d >>= 1) { s += __shfl_xor(s, d); q += __shfl_xor(q, d); }
  __shared__ float sb[8];
  const int wv = t >> 6;
  if ((t & 63) == 0) { sb[wv] = s; sb[4 + wv] = q; }
  __syncthreads();
  s = sb[0] + sb[1] + sb[2] + sb[3];
  q = sb[4] + sb[5] + sb[6] + sb[7];
  const float mu = s * (1.f / 1024.f);
  const float rstd = rsqrtf(q * (1.f / 1024.f) - mu * mu + 1e-5f);
  const float4 w4 = ((const float4*)wgt)[t];
  ushort4 o;
  o.x = f2bf((v.x - mu) * rstd * w4.x);
  o.y = f2bf((v.y - mu) * rstd * w4.y);
  o.z = f2bf((v.z - mu) * rstd * w4.z);
  o.w = f2bf((v.w - mu) * rstd * w4.w);
  *(ushort4*)(h2 + ro) = o;
}

// ---- reduce_out: out = x1 + sum(bf16 partials). one float4 per thread ---------------
__global__ __launch_bounds__(256) void reduce_out(const float* __restrict__ x1,
                                                  const u16* __restrict__ p, int nseg,
                                                  float* __restrict__ out) {
  const int i = blockIdx.x * blockDim.x + threadIdx.x;
  const size_t ro = (size_t)i * 4;
  float4 v = *(const float4*)(x1 + ro);
  for (int sgm = 0; sgm < nseg; ++sgm) {
    const ushort4 u = *(const ushort4*)(p + (size_t)sgm * 4096 * 1024 + ro);
    v.x += bf2f(u.x); v.y += bf2f(u.y); v.z += bf2f(u.z); v.w += bf2f(u.w);
  }
  *(float4*)(out + ro) = v;
}

// ---------------- 128x128 bf16 MFMA GEMM (R8-verified, unchanged) --------------------
template <int EPI>
__global__ __launch_bounds__(256) void gemm128(const u16* __restrict__ A,
                                               const u16* __restrict__ Bt,
                                               void* __restrict__ outp,
                                               int M, int N, int K) {
  __shared__ u16 As[2][4096];
  __shared__ u16 Bs[2][4096];
  const unsigned gx = gridDim.x, gy = gridDim.y, gxy = gx * gy;
  const unsigned nwg = gxy * gridDim.z;
  unsigned f = (blockIdx.z * gy + blockIdx.y) * gx + blockIdx.x;
  if ((nwg & 7u) == 0u) { const unsigned qq = nwg >> 3; f = (f & 7u) * qq + (f >> 3); }
  const int bx = f % gx, by = (f / gx) % gy, bz = f / gxy;

  const int t = threadIdx.x, w = t >> 6, l = t & 63;
  const int lr = l & 15, g = l >> 4;
  const int row0 = by * 128, col0 = bx * 128;
  const int segK = K / gridDim.z;
  const int k0 = bz * segK, kend = k0 + segK;
  const int wr = w >> 1, wc = w & 1;
  f32x4 acc[4][4] = {};

  const int sr = t >> 2;
  const int sk = (t & 3) << 3;
  const u16* Ag = A + (size_t)(row0 + sr) * K + sk;
  const u16* Bg = Bt + (size_t)(col0 + sr) * K + sk;
  const size_t rstride = (size_t)64 * K;

  auto stage = [&](int kt, int bb) {
    u16* AsW = As[bb] + w * 512;
    u16* BsW = Bs[bb] + w * 512;
    gl_lds16(Ag + kt, AsW);
    gl_lds16(Ag + kt + rstride, AsW + 2048);
    gl_lds16(Bg + kt, BsW);
    gl_lds16(Bg + kt + rstride, BsW + 2048);
  };

  stage(k0, 0);
  __syncthreads();
  int cur = 0;
  for (int kt = k0; kt < kend; kt += 32) {
    if (kt + 32 < kend) stage(kt + 32, cur ^ 1);
    bf16x8 af[4], bfr[4];
#pragma unroll
    for (int m = 0; m < 4; ++m)
      af[m] = *(const bf16x8*)(As[cur] + (wr * 64 + m * 16 + lr) * 32 + g * 8);
#pragma unroll
    for (int n = 0; n < 4; ++n)
      bfr[n] = *(const bf16x8*)(Bs[cur] + (wc * 64 + n * 16 + lr) * 32 + g * 8);
#pragma unroll
    for (int m = 0; m < 4; ++m)
#pragma unroll
      for (int n = 0; n < 4; ++n) acc[m][n] = mfma16(af[m], bfr[n], acc[m][n]);
    __syncthreads();
    cur ^= 1;
  }

  const size_t segoff = (size_t)bz * M * N;
#pragma unroll
  for (int m = 0; m < 4; ++m)
#pragma unroll
    for (int n = 0; n < 4; ++n)
#pragma unroll
      for (int r = 0; r < 4; ++r) {
        const int row = row0 + wr * 64 + m * 16 + g * 4 + r;
        const int col = col0 + wc * 64 + n * 16 + lr;
        const size_t idx = (size_t)row * N + col;
        const float v = acc[m][n][r];
        if constexpr (EPI == 0) ((u16*)outp)[idx] = f2bf(v);
        else if constexpr (EPI == 2) ((u16*)outp)[idx] = f2bf(fmaxf(v, 0.f));
        else ((u16*)outp)[segoff + idx] = f2bf(v);
      }
}

// ---------------- causal flash attention, bf16 MFMA ---------------------------------
// Swapped QK^T: z = mfma(K, Q) -> C[kv][q], q = lr (lane-local row). Softmax:
// in-lane 16-max + 2 cross-g shfl; defer-max (THR=8, log2 domain); packed b64 P-write.
// V single-buffered (write-after-PV + barrier): LDS 35.25KB -> 4 blocks/CU.
__global__ __launch_bounds__(256) void attn_fwd(const u16* __restrict__ qkvb,
                                                u16* __restrict__ y) {
  __shared__ u16 Ks[2][4096];     // 2 x 8KB, swizzled rows
  __shared__ u16 Vt[64 * 80];     // 10KB, [dh][kv] stride 80, single-buffered
  __shared__ u16 Pb[4][16 * 72];  // per-wave P: [q 0..15][kv 0..63], stride 72
  const int t = threadIdx.x, w = t >> 6, l = t & 63;
  const int lr = l & 15, g = l >> 4;
  const unsigned f = blockIdx.y * gridDim.x + blockIdx.x;
  const int xcd = f & 7, j = f >> 3;
  const int bh = xcd + 8 * (j & 3);
  const int qt = 31 - (j >> 2);
  const int b = bh >> 4, h = bh & 15;
  const size_t base = (size_t)b * 2048 * 3072;
  const u16* Kg = qkvb + base + 1024 + h * 64;
  const u16* Vg = qkvb + base + 2048 + h * 64;
  u16* Pw = &Pb[w][0];
  const int vkv = t & 63;
  const int vd0 = (t >> 6) * 16;
  const float SCL = 0.0450842200277855f;  // (1/32) * log2(e)

  auto stageK = [&](int kv0, int bb) {
#pragma unroll
    for (int r = 0; r < 2; ++r) {
      const int dl = (r * 256 + t) * 16;
      const int row = dl >> 7;
      const int srcb = (dl & 127) ^ ((row & 7) << 4);
      gl_lds16(Kg + (size_t)(kv0 + row) * 3072 + (srcb >> 1),
               (char*)Ks[bb] + r * 4096 + w * 1024);
    }
  };

  const int q0 = qt * 64, q0w = q0 + w * 16, nt = qt + 1;
  const u16* Qp = qkvb + base + (size_t)(q0w + lr) * 3072 + h * 64;
  const bf16x8 qf0 = *(const bf16x8*)(Qp + g * 8);
  const bf16x8 qf1 = *(const bf16x8*)(Qp + 32 + g * 8);
  f32x4 o[4] = {};
  float m1 = -1e30f, s1 = 0.f;  // per-lane: q = q0w + lr (log2 domain)

  stageK(0, 0);
  u16x8 v0 = *(const u16x8*)(Vg + (size_t)vkv * 3072 + vd0);
  u16x8 v1 = *(const u16x8*)(Vg + (size_t)vkv * 3072 + vd0 + 8);
#pragma unroll
  for (int jj = 0; jj < 8; ++jj) {
    Vt[(vd0 + jj) * 80 + vkv] = v0[jj];
    Vt[(vd0 + 8 + jj) * 80 + vkv] = v1[jj];
  }
  __syncthreads();

  int ct = 0;
  for (int tt = 0; tt < nt; ++tt) {
    const int kv0 = tt * 64;
    const bool more = (tt + 1 < nt);
    if (more) {
      stageK(kv0 + 64, ct ^ 1);
      v0 = *(const u16x8*)(Vg + (size_t)(kv0 + 64 + vkv) * 3072 + vd0);
      v1 = *(const u16x8*)(Vg + (size_t)(kv0 + 64 + vkv) * 3072 + vd0 + 8);
    }

    const u16* Kbuf = Ks[ct];
    // ---- QK^T swapped: A=K, B=Q -> s4[i][r] = S[kv0+i*16+g*4+r][q0w+lr] ----
    f32x4 s4[4];
#pragma unroll
    for (int i = 0; i < 4; ++i) {
      const int row = i * 16 + lr;
      const int sw = (row & 7) << 4;
      const bf16x8 k0 = *(const bf16x8*)(Kbuf + row * 64 + (((g * 16) ^ sw) >> 1));
      const bf16x8 k1 = *(const bf16x8*)(Kbuf + row * 64 + (((64 + g * 16) ^ sw) >> 1));
      f32x4 z = {0.f, 0.f, 0.f, 0.f};
      z = mfma16(k0, qf0, z);
      z = mfma16(k1, qf1, z);
      s4[i] = z * SCL;
    }
    if (kv0 + 64 > q0w) {  // causal: kv > q  (kv = kv0+i*16+g*4+r, q = q0w+lr)
#pragma unroll
      for (int i = 0; i < 4; ++i)
#pragma unroll
        for (int r = 0; r < 4; ++r)
          if (kv0 + i * 16 + g * 4 + r > q0w + lr) s4[i][r] = -1e30f;
    }
    // ---- softmax: in-lane 16-max, 2 cross-g shfl, defer-max ----
    const f32x4 mm = fmax4(fmax4(s4[0], s4[1]), fmax4(s4[2], s4[3]));
    float mx = fmaxf(fmaxf(mm[0], mm[1]), fmaxf(mm[2], mm[3]));
    mx = fmaxf(mx, __shfl_xor(mx, 16));
    mx = fmaxf(mx, __shfl_xor(mx, 32));
    if (!__all(mx <= m1 + 8.f)) {
      const float mn = fmaxf(m1, mx);
      const float sc = exp2f(m1 - mn);
      m1 = mn;
      s1 *= sc;
      float scr[4];
#pragma unroll
      for (int r = 0; r < 4; ++r) scr[r] = __shfl(sc, g * 4 + r);
#pragma unroll
      for (int n = 0; n < 4; ++n)
#pragma unroll
        for (int r = 0; r < 4; ++r) o[n][r] *= scr[r];
    }
    float ps = 0.f;
#pragma unroll
    for (int i = 0; i < 4; ++i) {
      u16x4 pk;
#pragma unroll
      for (int r = 0; r < 4; ++r) {
        const float p = exp2f(s4[i][r] - m1);
        ps += p;
        pk[r] = f2bf(p);
      }
      *(u16x4*)(Pw + lr * 72 + i * 16 + g * 4) = pk;  // packed b64 P-write
    }
    s1 += ps;
    // ---- PV: pa from LDS (same-wave), vf contiguous b128 from Vt ----
#pragma unroll
    for (int s = 0; s < 2; ++s) {
      const bf16x8 pa = *(const bf16x8*)(Pw + lr * 72 + s * 32 + g * 8);
#pragma unroll
      for (int n = 0; n < 4; ++n) {
        const bf16x8 vf = *(const bf16x8*)(&Vt[(n * 16 + lr) * 80 + s * 32 + g * 8]);
        o[n] = mfma16(pa, vf, o[n]);
      }
    }
    __syncthreads();  // all PV reads of Vt done
    if (more) {
#pragma unroll
      for (int jj = 0; jj < 8; ++jj) {
        Vt[(vd0 + jj) * 80 + vkv] = v0[jj];
        Vt[(vd0 + 8 + jj) * 80 + vkv] = v1[jj];
      }
    }
    __syncthreads();  // Vt ready for next tile; Ks[ct^1] drained (vmcnt at barrier)
    ct ^= 1;
  }

  // ---- epilogue: cross-g denominator, redistribute inverse, write y ----
  float den = s1;
  den += __shfl_xor(den, 16);
  den += __shfl_xor(den, 32);
  const float iv = 1.f / den;
  float ivr[4];
#pragma unroll
  for (int r = 0; r < 4; ++r) ivr[r] = __shfl(iv, g * 4 + r);
#pragma unroll
  for (int n = 0; n < 4; ++n)
#pragma unroll
    for (int r = 0; r < 4; ++r) {
      const int row = q0w + g * 4 + r;
      const int col = h * 64 + n * 16 + lr;
      y[(size_t)(b * 2048 + row) * 1024 + col] = f2bf(o[n][r] * ivr[r]);
    }
}

// ------------------------------------------------------------------------------------
// ws layout (MB), peak 120:
//   0..24  qkvb | later cprojP 0..32
//  24..32  h1   | later yb
//  32..48  projP (2 x 8MB)
//  48..64  x1 (f32)
//  64..72  h2
//  72..104 hf
// 104..112 wattnT(6)+wprojT(2) -> later wcprojT(8)
// 112..120 wfcT
extern "C" void kernel_launch(void* const* d_in, const int* in_sizes, int n_in,
                              void* d_out, int out_size, void* d_ws, size_t ws_size,
                              hipStream_t stream) {
  const float* x      = (const float*)d_in[0];
  const float* ln1w   = (const float*)d_in[1];
  const float* wattn  = (const float*)d_in[2];
  const float* wproj  = (const float*)d_in[3];
  const float* ln2w   = (const float*)d_in[4];
  const float* wfc    = (const float*)d_in[5];
  const float* wcproj = (const float*)d_in[6];
  float* out = (float*)d_out;
  char* ws = (char*)d_ws;
  const size_t MB = 1024 * 1024;
  u16* qkvb    = (u16*)(ws + 0);
  u16* cprojP  = (u16*)(ws + 0);
  u16* h1      = (u16*)(ws + 24 * MB);
  u16* yb      = (u16*)(ws + 24 * MB);
  u16* projP   = (u16*)(ws + 32 * MB);
  float* x1    = (float*)(ws + 48 * MB);
  u16* h2      = (u16*)(ws + 64 * MB);
  u16* hf      = (u16*)(ws + 72 * MB);
  u16* wattnT  = (u16*)(ws + 104 * MB);
  u16* wprojT  = (u16*)(ws + 110 * MB);
  u16* wcprojT = (u16*)(ws + 104 * MB);
  u16* wfcT    = (u16*)(ws + 112 * MB);

  convT<<<dim3(16, 48), 256, 0, stream>>>(wattn, wattnT, 1024, 3072);
  convT<<<dim3(16, 16), 256, 0, stream>>>(wproj, wprojT, 1024, 1024);
  convT<<<dim3(16, 64), 256, 0, stream>>>(wfc, wfcT, 1024, 4096);

  ln_bf16<<<4096, 256, 0, stream>>>(x, ln1w, h1);
  gemm128<0><<<dim3(24, 32, 1), 256, 0, stream>>>(h1, wattnT, qkvb, 4096, 3072, 1024);
  attn_fwd<<<dim3(32, 32), 256, 0, stream>>>(qkvb, yb);
  gemm128<4><<<dim3(8, 32, 2), 256, 0, stream>>>(yb, wprojT, projP, 4096, 1024, 1024);
  convT<<<dim3(64, 16), 256, 0, stream>>>(wcproj, wcprojT, 4096, 1024);
  reduce_ln<<<4096, 256, 0, stream>>>(x, projP, 2, ln2w, x1, h2);
  gemm128<2><<<dim3(32, 32, 1), 256, 0, stream>>>(h2, wfcT, hf, 4096, 4096, 1024);
  gemm128<4><<<dim3(8, 32, 4), 256, 0, stream>>>(hf, wcprojT, cprojP, 4096, 1024, 4096);
  reduce_out<<<4096, 256, 0, stream>>>(x1, cprojP, 4, out);
}